// Round 1
// baseline (5910.171 us; speedup 1.0000x reference)
//
#include <hip/hip_runtime.h>
#include <hip/hip_bf16.h>
#include <math.h>

// Problem constants (fixed by the reference)
#define NB 2
#define NL 2048
#define ND 1024
#define NH 16
#define NDH 64
#define NM (NB * NL)   // 4096 rows

// ---------------------------------------------------------------------------
// fp32 GEMM: C = scale * (A @ B)   A:(4096x1024) rm, B:(1024x1024) rm
// 128x128 block tile, BK=16, 256 threads, 8x8 per thread.
// ---------------------------------------------------------------------------
__device__ __forceinline__ void gemm_body(const float* __restrict__ A,
                                          const float* __restrict__ Bw,
                                          float* __restrict__ C,
                                          float scale, int bx, int by) {
  const int K = ND, N = ND;
  __shared__ float As[16][128];   // transposed A tile: As[kk][m]
  __shared__ float Bs[16][128];

  const int t  = threadIdx.x;
  const int tx = t & 15;          // 0..15 -> col block n0 = tx*8
  const int ty = t >> 4;          // 0..15 -> row block m0 = ty*8
  const int i0 = by * 128, j0 = bx * 128;

  float c[8][8];
#pragma unroll
  for (int i = 0; i < 8; ++i)
#pragma unroll
    for (int j = 0; j < 8; ++j) c[i][j] = 0.f;

  const int am = t >> 2;          // 0..63  (A row within tile; +64 second row)
  const int ak = (t & 3) * 4;     // 0,4,8,12
  const int bk = t >> 4;          // 0..15  (B row within tile)
  const int bn = (t & 15) * 4;    // 0..60

  for (int k0 = 0; k0 < K; k0 += 16) {
    float4 a0 = *(const float4*)(A + (size_t)(i0 + am)      * K + k0 + ak);
    float4 a1 = *(const float4*)(A + (size_t)(i0 + am + 64) * K + k0 + ak);
    float4 b0 = *(const float4*)(Bw + (size_t)(k0 + bk) * N + j0 + bn);
    float4 b1 = *(const float4*)(Bw + (size_t)(k0 + bk) * N + j0 + bn + 64);

    __syncthreads();   // protect previous iteration's LDS reads
    As[ak + 0][am] = a0.x; As[ak + 1][am] = a0.y;
    As[ak + 2][am] = a0.z; As[ak + 3][am] = a0.w;
    As[ak + 0][am + 64] = a1.x; As[ak + 1][am + 64] = a1.y;
    As[ak + 2][am + 64] = a1.z; As[ak + 3][am + 64] = a1.w;
    *(float4*)&Bs[bk][bn]      = b0;
    *(float4*)&Bs[bk][bn + 64] = b1;
    __syncthreads();

#pragma unroll
    for (int kk = 0; kk < 16; ++kk) {
      float4 a04 = *(const float4*)&As[kk][ty * 8];
      float4 a14 = *(const float4*)&As[kk][ty * 8 + 4];
      float4 b04 = *(const float4*)&Bs[kk][tx * 8];
      float4 b14 = *(const float4*)&Bs[kk][tx * 8 + 4];
      float av[8] = {a04.x, a04.y, a04.z, a04.w, a14.x, a14.y, a14.z, a14.w};
      float bv[8] = {b04.x, b04.y, b04.z, b04.w, b14.x, b14.y, b14.z, b14.w};
#pragma unroll
      for (int i = 0; i < 8; ++i)
#pragma unroll
        for (int j = 0; j < 8; ++j) c[i][j] += av[i] * bv[j];
    }
  }

#pragma unroll
  for (int i = 0; i < 8; ++i) {
    float* cp = C + (size_t)(i0 + ty * 8 + i) * N + j0 + tx * 8;
    float4 o0 = make_float4(c[i][0] * scale, c[i][1] * scale,
                            c[i][2] * scale, c[i][3] * scale);
    float4 o1 = make_float4(c[i][4] * scale, c[i][5] * scale,
                            c[i][6] * scale, c[i][7] * scale);
    *(float4*)cp       = o0;
    *(float4*)(cp + 4) = o1;
  }
}

__global__ __launch_bounds__(256) void gemm_qkv(const float* __restrict__ X,
                                                const float* __restrict__ Wq,
                                                const float* __restrict__ Wk,
                                                const float* __restrict__ Wv,
                                                float* __restrict__ Q,
                                                float* __restrict__ K,
                                                float* __restrict__ V) {
  const float* Bw;
  float* C;
  float scale;
  if (blockIdx.z == 0)      { Bw = Wq; C = Q; scale = 0.03125f; }  // 1/sqrt(1024)
  else if (blockIdx.z == 1) { Bw = Wk; C = K; scale = 1.f; }
  else                      { Bw = Wv; C = V; scale = 1.f; }
  gemm_body(X, Bw, C, scale, blockIdx.x, blockIdx.y);
}

__global__ __launch_bounds__(256) void gemm_out(const float* __restrict__ A,
                                                const float* __restrict__ Bw,
                                                float* __restrict__ C) {
  gemm_body(A, Bw, C, 1.f, blockIdx.x, blockIdx.y);
}

// ---------------------------------------------------------------------------
// RoPE (interleaved), in place on Q and K. One thread per (even,odd) pair.
// ---------------------------------------------------------------------------
__global__ __launch_bounds__(256) void rope_f32(float* __restrict__ Q,
                                                float* __restrict__ Kt) {
  const int PR  = ND / 2;        // 512 pairs per row
  const int TOT = NM * PR;       // per tensor
  int idx = blockIdx.x * 256 + threadIdx.x;
  float* base = (idx < TOT) ? Q : Kt;
  int e = (idx < TOT) ? idx : idx - TOT;
  int row = e >> 9;              // /512
  int pr  = e & (PR - 1);
  int l   = row & (NL - 1);      // position within sequence
  int p   = pr & (NDH / 2 - 1);  // pair index within head: 0..31
  // inv_freq = 10000^(-2p/64) = exp(-p * ln(10000)/32)
  float inv_freq = expf(-(float)p * 0.2878231366f);
  float ang = (float)l * inv_freq;
  float sn, cs;
  sincosf(ang, &sn, &cs);
  float2* ptr = (float2*)(base + (size_t)row * ND + 2 * pr);
  float2 v = *ptr;
  float2 o = make_float2(v.x * cs - v.y * sn, v.y * cs + v.x * sn);
  *ptr = o;
}

// ---------------------------------------------------------------------------
// Causal flash attention, fp32. One block = 64 query rows of one (b,h).
// Thread (r = t>>2, g = t&3): row r, key-cols / out-dims [g*16, g*16+16).
// q row held in registers; K/V read direct from global (L1/L2-resident tiles);
// P exchanged via padded LDS (stride 68 -> conflict-free), intra-wave only.
// NOTE: Y may alias Q (each block reads exactly the Q region it overwrites,
// reads complete before the final write) -- so no __restrict__ on Q/Y.
// ---------------------------------------------------------------------------
__global__ __launch_bounds__(256) void attn_f32(const float* Q,
                                                const float* __restrict__ K,
                                                const float* __restrict__ V,
                                                float* Y) {
  const int qt = blockIdx.x;       // 0..31 query tile
  const int bh = blockIdx.y;       // 0..31
  const int b = bh >> 4, h = bh & (NH - 1);
  const int t = threadIdx.x;
  const int r = t >> 2;            // 0..63
  const int g = t & 3;             // 0..3

  __shared__ float Ps[64][68];     // pad 68: bank = (4r + c) % 32, conflict-free

  const size_t qrow = (size_t)(b * NL + qt * 64 + r);
  const float4* qp = (const float4*)(Q + qrow * ND + h * NDH);
  float4 q[16];
#pragma unroll
  for (int i = 0; i < 16; ++i) q[i] = qp[i];

  float yacc[16];
#pragma unroll
  for (int i = 0; i < 16; ++i) yacc[i] = 0.f;
  float m_run = -1e30f, l_run = 0.f;
  const int ig = qt * 64 + r;

  const size_t kvbase = (size_t)(b * NL) * ND + h * NDH;

  for (int kt = 0; kt <= qt; ++kt) {
    // ---- S = q . k for 16 key cols c = g*16+m
    float s[16];
#pragma unroll 4
    for (int m = 0; m < 16; ++m) {
      const int c = g * 16 + m;
      const float4* kp = (const float4*)(K + kvbase + (size_t)(kt * 64 + c) * ND);
      float sv = 0.f;
#pragma unroll
      for (int d = 0; d < 16; ++d) {
        float4 kv = kp[d];
        sv += q[d].x * kv.x; sv += q[d].y * kv.y;
        sv += q[d].z * kv.z; sv += q[d].w * kv.w;
      }
      s[m] = sv;
    }
    // ---- causal mask (diagonal tile only)
    if (kt == qt) {
#pragma unroll
      for (int m = 0; m < 16; ++m)
        if (kt * 64 + g * 16 + m > ig) s[m] = -1e30f;
    }
    // ---- online softmax (row split across 4 lanes; reduce via shfl_xor 1,2)
    float mx = s[0];
#pragma unroll
    for (int m = 1; m < 16; ++m) mx = fmaxf(mx, s[m]);
    mx = fmaxf(mx, __shfl_xor(mx, 1));
    mx = fmaxf(mx, __shfl_xor(mx, 2));
    const float m_new = fmaxf(m_run, mx);
    const float corr = __expf(m_run - m_new);
    float ps = 0.f;
#pragma unroll
    for (int m = 0; m < 16; ++m) {
      float p = __expf(s[m] - m_new);
      s[m] = p;
      ps += p;
    }
    ps += __shfl_xor(ps, 1);
    ps += __shfl_xor(ps, 2);
    l_run = l_run * corr + ps;
    m_run = m_new;
#pragma unroll
    for (int i = 0; i < 16; ++i) yacc[i] *= corr;

    // ---- publish P row-slice to LDS (intra-wave exchange; rows per wave are
    //      disjoint -> no barrier needed; same-array aliasing keeps order)
#pragma unroll
    for (int m4 = 0; m4 < 4; ++m4)
      *(float4*)&Ps[r][g * 16 + m4 * 4] =
          make_float4(s[m4 * 4], s[m4 * 4 + 1], s[m4 * 4 + 2], s[m4 * 4 + 3]);

    // ---- PV: yacc[e] += sum_c P[r][c] * V[c][g*16+e]
#pragma unroll 4
    for (int c = 0; c < 64; ++c) {
      const float p = Ps[r][c];
      const float4* vp =
          (const float4*)(V + kvbase + (size_t)(kt * 64 + c) * ND + g * 16);
      float4 v0 = vp[0], v1 = vp[1], v2 = vp[2], v3 = vp[3];
      yacc[0]  += p * v0.x; yacc[1]  += p * v0.y;
      yacc[2]  += p * v0.z; yacc[3]  += p * v0.w;
      yacc[4]  += p * v1.x; yacc[5]  += p * v1.y;
      yacc[6]  += p * v1.z; yacc[7]  += p * v1.w;
      yacc[8]  += p * v2.x; yacc[9]  += p * v2.y;
      yacc[10] += p * v2.z; yacc[11] += p * v2.w;
      yacc[12] += p * v3.x; yacc[13] += p * v3.y;
      yacc[14] += p * v3.z; yacc[15] += p * v3.w;
    }
  }

  const float invl = 1.f / l_run;   // diagonal is always unmasked -> l_run > 0
  float* yp = Y + qrow * ND + h * NDH + g * 16;
#pragma unroll
  for (int m4 = 0; m4 < 4; ++m4)
    *(float4*)(yp + m4 * 4) =
        make_float4(yacc[m4 * 4] * invl, yacc[m4 * 4 + 1] * invl,
                    yacc[m4 * 4 + 2] * invl, yacc[m4 * 4 + 3] * invl);
}

// ---------------------------------------------------------------------------
extern "C" void kernel_launch(void* const* d_in, const int* in_sizes, int n_in,
                              void* d_out, int out_size, void* d_ws,
                              size_t ws_size, hipStream_t stream) {
  const float* x  = (const float*)d_in[0];
  const float* Wq = (const float*)d_in[1];
  const float* Wk = (const float*)d_in[2];
  const float* Wv = (const float*)d_in[3];
  const float* Wo = (const float*)d_in[4];
  float* out = (float*)d_out;

  // workspace: Q | K | V  (3 x 16MB = 48MB). Y reuses Q (alias-safe per block).
  float* Q = (float*)d_ws;
  float* K = Q + (size_t)NM * ND;
  float* V = K + (size_t)NM * ND;

  dim3 blk(256);

  // 1) QKV projections (q pre-scaled by 1/sqrt(d))
  gemm_qkv<<<dim3(ND / 128, NM / 128, 3), blk, 0, stream>>>(x, Wq, Wk, Wv, Q, K, V);

  // 2) RoPE in place on Q and K
  rope_f32<<<dim3(2 * NM * (ND / 2) / 256), blk, 0, stream>>>(Q, K);

  // 3) causal attention; Y overwrites Q
  attn_f32<<<dim3(NL / 64, NB * NH), blk, 0, stream>>>(Q, K, V, Q);

  // 4) output projection
  gemm_out<<<dim3(ND / 128, NM / 128, 1), blk, 0, stream>>>(Q, Wo, out);
}

// Round 2
// 593.767 us; speedup vs baseline: 9.9537x; 9.9537x over previous
//
#include <hip/hip_runtime.h>
#include <hip/hip_bf16.h>
#include <math.h>

#define NB 2
#define NL 2048
#define ND 1024
#define NH 16
#define NDH 64
#define NM (NB * NL)   // 4096 rows

typedef __bf16 bf16x8 __attribute__((ext_vector_type(8)));
typedef float  f32x4  __attribute__((ext_vector_type(4)));

union FragU { unsigned int u[4]; bf16x8 v; };

__device__ __forceinline__ unsigned int f2bf(float f) {   // RTNE f32 -> bf16 bits
  unsigned int u = __float_as_uint(f);
  return (u + 0x7fffu + ((u >> 16) & 1u)) >> 16;
}
__device__ __forceinline__ float bf2f(unsigned int b) {
  return __uint_as_float(b << 16);
}

// ---------------------------------------------------------------------------
// fp32 GEMM body: 128x128 tile, BK=16, 256 thr, 8x8/thread. BF16OUT selects
// bf16-packed epilogue (for Q/K/V) vs fp32 (final output).
// ---------------------------------------------------------------------------
template <bool BF16OUT>
__device__ __forceinline__ void gemm_body(const float* __restrict__ A,
                                          const float* __restrict__ Bw,
                                          void* __restrict__ Cv,
                                          float scale, int bx, int by) {
  const int K = ND, N = ND;
  __shared__ float As[16][128];
  __shared__ float Bs[16][128];

  const int t  = threadIdx.x;
  const int tx = t & 15;
  const int ty = t >> 4;
  const int i0 = by * 128, j0 = bx * 128;

  float c[8][8];
#pragma unroll
  for (int i = 0; i < 8; ++i)
#pragma unroll
    for (int j = 0; j < 8; ++j) c[i][j] = 0.f;

  const int am = t >> 2;
  const int ak = (t & 3) * 4;
  const int bk = t >> 4;
  const int bn = (t & 15) * 4;

  for (int k0 = 0; k0 < K; k0 += 16) {
    float4 a0 = *(const float4*)(A + (size_t)(i0 + am)      * K + k0 + ak);
    float4 a1 = *(const float4*)(A + (size_t)(i0 + am + 64) * K + k0 + ak);
    float4 b0 = *(const float4*)(Bw + (size_t)(k0 + bk) * N + j0 + bn);
    float4 b1 = *(const float4*)(Bw + (size_t)(k0 + bk) * N + j0 + bn + 64);

    __syncthreads();
    As[ak + 0][am] = a0.x; As[ak + 1][am] = a0.y;
    As[ak + 2][am] = a0.z; As[ak + 3][am] = a0.w;
    As[ak + 0][am + 64] = a1.x; As[ak + 1][am + 64] = a1.y;
    As[ak + 2][am + 64] = a1.z; As[ak + 3][am + 64] = a1.w;
    *(float4*)&Bs[bk][bn]      = b0;
    *(float4*)&Bs[bk][bn + 64] = b1;
    __syncthreads();

#pragma unroll
    for (int kk = 0; kk < 16; ++kk) {
      float4 a04 = *(const float4*)&As[kk][ty * 8];
      float4 a14 = *(const float4*)&As[kk][ty * 8 + 4];
      float4 b04 = *(const float4*)&Bs[kk][tx * 8];
      float4 b14 = *(const float4*)&Bs[kk][tx * 8 + 4];
      float av[8] = {a04.x, a04.y, a04.z, a04.w, a14.x, a14.y, a14.z, a14.w};
      float bv[8] = {b04.x, b04.y, b04.z, b04.w, b14.x, b14.y, b14.z, b14.w};
#pragma unroll
      for (int i = 0; i < 8; ++i)
#pragma unroll
        for (int j = 0; j < 8; ++j) c[i][j] += av[i] * bv[j];
    }
  }

  if (BF16OUT) {
    unsigned short* Cb = (unsigned short*)Cv;
#pragma unroll
    for (int i = 0; i < 8; ++i) {
      uint4 o;
      o.x = f2bf(c[i][0] * scale) | (f2bf(c[i][1] * scale) << 16);
      o.y = f2bf(c[i][2] * scale) | (f2bf(c[i][3] * scale) << 16);
      o.z = f2bf(c[i][4] * scale) | (f2bf(c[i][5] * scale) << 16);
      o.w = f2bf(c[i][6] * scale) | (f2bf(c[i][7] * scale) << 16);
      *(uint4*)(Cb + (size_t)(i0 + ty * 8 + i) * N + j0 + tx * 8) = o;
    }
  } else {
    float* Cf = (float*)Cv;
#pragma unroll
    for (int i = 0; i < 8; ++i) {
      float* cp = Cf + (size_t)(i0 + ty * 8 + i) * N + j0 + tx * 8;
      *(float4*)cp = make_float4(c[i][0] * scale, c[i][1] * scale,
                                 c[i][2] * scale, c[i][3] * scale);
      *(float4*)(cp + 4) = make_float4(c[i][4] * scale, c[i][5] * scale,
                                       c[i][6] * scale, c[i][7] * scale);
    }
  }
}

__global__ __launch_bounds__(256) void gemm_qkv(const float* __restrict__ X,
                                                const float* __restrict__ Wq,
                                                const float* __restrict__ Wk,
                                                const float* __restrict__ Wv,
                                                unsigned short* __restrict__ Qb,
                                                unsigned short* __restrict__ Kb,
                                                unsigned short* __restrict__ Vb) {
  const float* Bw;
  unsigned short* C;
  float scale;
  // q scale = 1/sqrt(1024) * log2(e)  (softmax runs in base-2 domain)
  if (blockIdx.z == 0)      { Bw = Wq; C = Qb; scale = 0.03125f * 1.44269504f; }
  else if (blockIdx.z == 1) { Bw = Wk; C = Kb; scale = 1.f; }
  else                      { Bw = Wv; C = Vb; scale = 1.f; }
  gemm_body<true>(X, Bw, C, scale, blockIdx.x, blockIdx.y);
}

__global__ __launch_bounds__(256) void gemm_out(const float* __restrict__ A,
                                                const float* __restrict__ Bw,
                                                float* __restrict__ C) {
  gemm_body<false>(A, Bw, C, 1.f, blockIdx.x, blockIdx.y);
}

// ---------------------------------------------------------------------------
// RoPE cos/sin table: tab[l*32+p] = bf16(cos)|bf16(sin)<<16, angle = l*10000^(-p/32)
// ---------------------------------------------------------------------------
__global__ __launch_bounds__(256) void rope_tab(unsigned int* __restrict__ tab) {
  int i = blockIdx.x * 256 + threadIdx.x;      // 0..65535
  int l = i >> 5, p = i & 31;
  float invf = expf(-(float)p * 0.28782313662425572f);   // ln(10000)/32
  float ang = (float)l * invf;
  float sn, cs;
  sincosf(ang, &sn, &cs);
  tab[i] = f2bf(cs) | (f2bf(sn) << 16);
}

// ---------------------------------------------------------------------------
// RoPE applied in place to bf16 Q and K. One thread = one uint4 (8 bf16 = 4 pairs).
// ---------------------------------------------------------------------------
__global__ __launch_bounds__(256) void rope_apply(unsigned int* __restrict__ Qb,
                                                  unsigned int* __restrict__ Kb,
                                                  const unsigned int* __restrict__ tab) {
  const int PER = NM * (ND / 8);               // 524288 uint4 per tensor
  int i = blockIdx.x * 256 + threadIdx.x;
  uint4* base = (uint4*)Qb;
  if (i >= PER) { base = (uint4*)Kb; i -= PER; }
  int row = i >> 7;                            // 128 chunks per row
  int ch  = i & 127;
  int l   = row & (NL - 1);
  int p0  = (ch & 7) * 4;                      // first pair index within head
  uint4 v = base[i];
  const unsigned int* tp = tab + l * 32 + p0;
  unsigned int vv[4] = {v.x, v.y, v.z, v.w};
  unsigned int oo[4];
#pragma unroll
  for (int j = 0; j < 4; ++j) {
    unsigned int cs = tp[j];
    float c = bf2f(cs & 0xffffu), s = bf2f(cs >> 16);
    float x0 = bf2f(vv[j] & 0xffffu), x1 = bf2f(vv[j] >> 16);
    float o0 = x0 * c - x1 * s;
    float o1 = x1 * c + x0 * s;
    oo[j] = f2bf(o0) | (f2bf(o1) << 16);
  }
  base[i] = make_uint4(oo[0], oo[1], oo[2], oo[3]);
}

// ---------------------------------------------------------------------------
// V transpose: Vb[b,l,h,d] bf16 -> Vt[(b,h), d, l] bf16 (row = head dim, col = seq)
// ---------------------------------------------------------------------------
__global__ __launch_bounds__(256) void vtrans(const unsigned short* __restrict__ Vb,
                                              unsigned short* __restrict__ Vt) {
  __shared__ unsigned short Ls[64][80];
  const int bh = blockIdx.y;                   // 0..31
  const int lt = blockIdx.x;                   // 0..31
  const int b = bh >> 4, h = bh & 15;
  const int t = threadIdx.x;
  const int l0 = lt * 64;
#pragma unroll
  for (int rep = 0; rep < 2; ++rep) {
    int idx = rep * 256 + t;
    int lrow = idx >> 3, c8 = idx & 7;
    uint4 v = *(const uint4*)(Vb + (size_t)(b * NL + l0 + lrow) * ND + h * 64 + c8 * 8);
    *(uint4*)&Ls[lrow][c8 * 8] = v;            // row stride 160B (16B multiple)
  }
  __syncthreads();
#pragma unroll
  for (int rep = 0; rep < 2; ++rep) {
    int idx = rep * 256 + t;
    int d = idx >> 3, lq = idx & 7;
    unsigned int w[4];
#pragma unroll
    for (int jj = 0; jj < 4; ++jj)
      w[jj] = (unsigned int)Ls[lq * 8 + 2 * jj][d] |
              ((unsigned int)Ls[lq * 8 + 2 * jj + 1][d] << 16);
    *(uint4*)(Vt + (size_t)(bh * 64 + d) * NL + l0 + lq * 8) =
        make_uint4(w[0], w[1], w[2], w[3]);
  }
}

// ---------------------------------------------------------------------------
// Causal flash attention, bf16 MFMA (16x16x32), fp32 accum, base-2 softmax.
// Block = 256 thr = 4 waves; wave w owns q rows [qt*64+w*16, +16).
// KV tiles of 64 keys staged in LDS in *fragment order* (16B chunk per
// (frag,lane) -> ds_read_b128 / ds_write_b128, conflict-free).
// Swapped QK^T: S^T = mfma(A=K, B=Q)  =>  lane holds P[row=lo][16 keys]
// which is exactly PV's A-fragment (no LDS round trip for P).
// Fragment layouts (gfx950 16x16x32 bf16):
//   A[row=l&15][k=(l>>4)*4+j  (j=0..3) | 16+(l>>4)*4+(j-4) (j=4..7)]
//   B[k (same)][col=l&15]
//   D[row=(l>>4)*4+reg][col=l&15]   (verified layout)
// ---------------------------------------------------------------------------
__global__ __launch_bounds__(256, 4) void attn_mfma(
    const unsigned short* __restrict__ Qb,
    const unsigned short* __restrict__ Kb,
    const unsigned short* __restrict__ Vt,
    float* __restrict__ Y) {
  __shared__ uint4 Ks[512];   // 8KB: chunk c = (kg*2+c32)*64 + lane
  __shared__ uint4 Vs[512];   // 8KB: chunk c = (et*2+h2)*64 + lane

  const int qt = (int)gridDim.x - 1 - (int)blockIdx.x;   // heavy blocks first
  const int bh = blockIdx.y;
  const int b = bh >> 4, h = bh & 15;
  const int t = threadIdx.x;
  const int w = t >> 6, l = t & 63;
  const int lo = l & 15, hi = l >> 4;
  const int hi4 = hi * 4;

  // ---- Q B-fragments (2 K-chunks of d), per lane: row lo of this wave's 16
  const int qrow = qt * 64 + w * 16 + lo;
  const char* qc = (const char*)(Qb + ((size_t)(b * NL + qrow)) * ND + h * 64);
  FragU qf[2];
  {
    uint2 a0 = *(const uint2*)(qc + hi * 8);
    uint2 b0 = *(const uint2*)(qc + hi * 8 + 32);
    uint2 a1 = *(const uint2*)(qc + hi * 8 + 64);
    uint2 b1 = *(const uint2*)(qc + hi * 8 + 96);
    qf[0].u[0] = a0.x; qf[0].u[1] = a0.y; qf[0].u[2] = b0.x; qf[0].u[3] = b0.y;
    qf[1].u[0] = a1.x; qf[1].u[1] = a1.y; qf[1].u[2] = b1.x; qf[1].u[3] = b1.y;
  }

  // ---- per-thread staging decode (2 chunks per thread per array)
  const char* kbase = (const char*)(Kb + (size_t)b * NL * ND + h * 64);
  const char* vbase = (const char*)(Vt + (size_t)bh * 64 * NL);
  const char* pK[2];
  const char* pV[2];
  int cid[2];
#pragma unroll
  for (int r = 0; r < 2; ++r) {
    int c = r * 256 + t;                 // 0..511
    cid[r] = c;
    int lc = c & 63;
    int pair = c >> 6;                   // 0..7
    int g16 = pair >> 1;                 // kg (K) / et (V)
    int c32 = pair & 1;
    int row = g16 * 16 + (lc & 15);
    int offA = c32 * 64 + ((lc >> 4) << 3);
    pK[r] = kbase + (size_t)row * (ND * 2) + offA;        // + kt*64 rows later
    pV[r] = vbase + (size_t)row * (NL * 2) + offA;        // + kt*128 bytes later
  }

  f32x4 yacc[4];
#pragma unroll
  for (int et = 0; et < 4; ++et) yacc[et] = (f32x4){0.f, 0.f, 0.f, 0.f};
  float m_run = -1e30f, l_run = 0.f;

  for (int kt = 0; kt <= qt; ++kt) {
    __syncthreads();                     // prior tile's LDS reads complete
    // ---- stage K and Vt tiles into LDS (fragment order)
#pragma unroll
    for (int r = 0; r < 2; ++r) {
      const char* sk = pK[r] + (size_t)kt * (64 * ND * 2);
      uint2 ka = *(const uint2*)sk;
      uint2 kb2 = *(const uint2*)(sk + 32);
      Ks[cid[r]] = make_uint4(ka.x, ka.y, kb2.x, kb2.y);
      const char* sv = pV[r] + (size_t)kt * 128;
      uint2 va = *(const uint2*)sv;
      uint2 vb2 = *(const uint2*)(sv + 32);
      Vs[cid[r]] = make_uint4(va.x, va.y, vb2.x, vb2.y);
    }
    __syncthreads();

    // ---- S^T = K * Q^T : sacc[kg][reg] = S[qrow=lo][key = kg*16 + hi4 + reg]
    f32x4 sacc[4];
#pragma unroll
    for (int kg = 0; kg < 4; ++kg) {
      sacc[kg] = (f32x4){0.f, 0.f, 0.f, 0.f};
#pragma unroll
      for (int c32 = 0; c32 < 2; ++c32) {
        FragU kf;
        *(uint4*)kf.u = Ks[(kg * 2 + c32) * 64 + l];
        sacc[kg] = __builtin_amdgcn_mfma_f32_16x16x32_bf16(kf.v, qf[c32].v,
                                                           sacc[kg], 0, 0, 0);
      }
    }

    // ---- causal mask (diagonal tile only)
    if (kt == qt) {
#pragma unroll
      for (int kg = 0; kg < 4; ++kg)
#pragma unroll
        for (int reg = 0; reg < 4; ++reg) {
          int key = kt * 64 + kg * 16 + hi4 + reg;
          if (key > qrow) sacc[kg][reg] = -1e30f;
        }
    }

    // ---- online softmax (base 2); row lo's values live in lanes lo,lo+16,lo+32,lo+48
    float mt = sacc[0][0];
#pragma unroll
    for (int kg = 0; kg < 4; ++kg)
#pragma unroll
      for (int reg = 0; reg < 4; ++reg) mt = fmaxf(mt, sacc[kg][reg]);
    mt = fmaxf(mt, __shfl_xor(mt, 16));
    mt = fmaxf(mt, __shfl_xor(mt, 32));
    float mnew = fmaxf(m_run, mt);
    float corr = exp2f(m_run - mnew);
    float ps = 0.f;
#pragma unroll
    for (int kg = 0; kg < 4; ++kg)
#pragma unroll
      for (int reg = 0; reg < 4; ++reg) {
        float e = exp2f(sacc[kg][reg] - mnew);
        sacc[kg][reg] = e;
        ps += e;
      }
    ps += __shfl_xor(ps, 16);
    ps += __shfl_xor(ps, 32);
    l_run = l_run * corr + ps;
    m_run = mnew;

    // rescale yacc rows (row = hi4+reg, its corr lives in lane hi4+reg)
    float c0 = __shfl(corr, hi4 + 0);
    float c1 = __shfl(corr, hi4 + 1);
    float c2 = __shfl(corr, hi4 + 2);
    float c3 = __shfl(corr, hi4 + 3);
#pragma unroll
    for (int et = 0; et < 4; ++et) {
      yacc[et][0] *= c0; yacc[et][1] *= c1;
      yacc[et][2] *= c2; yacc[et][3] *= c3;
    }

    // ---- P fragments (A-operand) straight from registers
    FragU pa0, pa1;
    pa0.u[0] = f2bf(sacc[0][0]) | (f2bf(sacc[0][1]) << 16);
    pa0.u[1] = f2bf(sacc[0][2]) | (f2bf(sacc[0][3]) << 16);
    pa0.u[2] = f2bf(sacc[1][0]) | (f2bf(sacc[1][1]) << 16);
    pa0.u[3] = f2bf(sacc[1][2]) | (f2bf(sacc[1][3]) << 16);
    pa1.u[0] = f2bf(sacc[2][0]) | (f2bf(sacc[2][1]) << 16);
    pa1.u[1] = f2bf(sacc[2][2]) | (f2bf(sacc[2][3]) << 16);
    pa1.u[2] = f2bf(sacc[3][0]) | (f2bf(sacc[3][1]) << 16);
    pa1.u[3] = f2bf(sacc[3][2]) | (f2bf(sacc[3][3]) << 16);

    // ---- PV: yacc[et] += P * V   (B-frag from Vt tile in LDS)
#pragma unroll
    for (int et = 0; et < 4; ++et) {
      FragU vf0, vf1;
      *(uint4*)vf0.u = Vs[(et * 2 + 0) * 64 + l];
      *(uint4*)vf1.u = Vs[(et * 2 + 1) * 64 + l];
      yacc[et] = __builtin_amdgcn_mfma_f32_16x16x32_bf16(pa0.v, vf0.v, yacc[et], 0, 0, 0);
      yacc[et] = __builtin_amdgcn_mfma_f32_16x16x32_bf16(pa1.v, vf1.v, yacc[et], 0, 0, 0);
    }
  }

  // ---- epilogue: divide by row sums, write Y fp32
  float li0 = 1.f / __shfl(l_run, hi4 + 0);
  float li1 = 1.f / __shfl(l_run, hi4 + 1);
  float li2 = 1.f / __shfl(l_run, hi4 + 2);
  float li3 = 1.f / __shfl(l_run, hi4 + 3);
  const size_t ybase = (size_t)(b * NL + qt * 64 + w * 16) * ND + h * 64;
#pragma unroll
  for (int et = 0; et < 4; ++et) {
    Y[ybase + (size_t)(hi4 + 0) * ND + et * 16 + lo] = yacc[et][0] * li0;
    Y[ybase + (size_t)(hi4 + 1) * ND + et * 16 + lo] = yacc[et][1] * li1;
    Y[ybase + (size_t)(hi4 + 2) * ND + et * 16 + lo] = yacc[et][2] * li2;
    Y[ybase + (size_t)(hi4 + 3) * ND + et * 16 + lo] = yacc[et][3] * li3;
  }
}

// ---------------------------------------------------------------------------
extern "C" void kernel_launch(void* const* d_in, const int* in_sizes, int n_in,
                              void* d_out, int out_size, void* d_ws,
                              size_t ws_size, hipStream_t stream) {
  const float* x  = (const float*)d_in[0];
  const float* Wq = (const float*)d_in[1];
  const float* Wk = (const float*)d_in[2];
  const float* Wv = (const float*)d_in[3];
  const float* Wo = (const float*)d_in[4];
  float* out = (float*)d_out;

  // workspace: Qb|Kb|Vb|Vt (bf16, 8MB each) | Y (fp32 16MB). tab overlaps Y
  // (used only before attn writes Y). Total = 48MB (same as round 1).
  unsigned short* Qb = (unsigned short*)d_ws;
  unsigned short* Kb = Qb + (size_t)NM * ND;
  unsigned short* Vb = Kb + (size_t)NM * ND;
  unsigned short* Vt = Vb + (size_t)NM * ND;
  float* Yf = (float*)(Vt + (size_t)NM * ND);
  unsigned int* tab = (unsigned int*)Yf;

  dim3 blk(256);

  gemm_qkv<<<dim3(ND / 128, NM / 128, 3), blk, 0, stream>>>(x, Wq, Wk, Wv, Qb, Kb, Vb);
  rope_tab<<<dim3(NL * 32 / 256), blk, 0, stream>>>(tab);
  rope_apply<<<dim3(2 * NM * (ND / 8) / 256), blk, 0, stream>>>(
      (unsigned int*)Qb, (unsigned int*)Kb, tab);
  vtrans<<<dim3(NL / 64, NB * NH), blk, 0, stream>>>(Vb, Vt);
  attn_mfma<<<dim3(NL / 64, NB * NH), blk, 0, stream>>>(Qb, Kb, Vt, Yf);
  gemm_out<<<dim3(ND / 128, NM / 128, 1), blk, 0, stream>>>(Yf, Wo, out);
}

// Round 3
// 225.691 us; speedup vs baseline: 26.1870x; 2.6309x over previous
//
#include <hip/hip_runtime.h>
#include <hip/hip_bf16.h>
#include <math.h>

#define NB 2
#define NL 2048
#define ND 1024
#define NH 16
#define NDH 64
#define NM (NB * NL)   // 4096 rows

typedef __bf16 bf16x8 __attribute__((ext_vector_type(8)));
typedef float  f32x4  __attribute__((ext_vector_type(4)));
typedef unsigned int   u32;
typedef unsigned short u16;

union FragU { u32 u[4]; bf16x8 v; };

__device__ __forceinline__ u32 f2bf(float f) {   // RTNE f32 -> bf16 bits
  u32 u = __float_as_uint(f);
  return (u + 0x7fffu + ((u >> 16) & 1u)) >> 16;
}
__device__ __forceinline__ float bf2f(u32 b) { return __uint_as_float(b << 16); }

// async global->LDS, 16B per lane; LDS dest wave-uniform base + lane*16
__device__ __forceinline__ void gload16(const void* g, void* l) {
  __builtin_amdgcn_global_load_lds(
      (const __attribute__((address_space(1))) u32*)g,
      (__attribute__((address_space(3))) u32*)l, 16, 0, 0);
}

// ===========================================================================
// Packed operand layout (validated by attn's Ks staging in round 2):
//   P[rb][kc][lane] : 16B chunk, rb = 16-row block, kc = 32-col(k) chunk
//   chunk(rb,kc,l) = { src[16rb+(l&15)][32kc+4(l>>4)+0..3],
//                      src[16rb+(l&15)][32kc+16+4(l>>4)+0..3] }  (bf16)
// This is exactly one lane's A-frag (rows) / B-frag (cols) for
// mfma_f32_16x16x32_bf16, so LDS staging is linear and reads are b128.
// ===========================================================================

// shared emit phase: Ls[16][1032] bf16 -> 32 kc * 64 lane chunks
__device__ __forceinline__ void pack_emit(const u16 Ls[16][1032],
                                          uint4* __restrict__ dst, int t) {
#pragma unroll
  for (int rep = 0; rep < 8; ++rep) {
    int c  = rep * 256 + t;          // 0..2047
    int kc = c >> 6, l = c & 63;
    int lo = l & 15, hi = l >> 4;
    int k0 = kc * 32 + hi * 4;
    uint4 o;
    o.x = (u32)Ls[lo][k0 + 0]  | ((u32)Ls[lo][k0 + 1]  << 16);
    o.y = (u32)Ls[lo][k0 + 2]  | ((u32)Ls[lo][k0 + 3]  << 16);
    o.z = (u32)Ls[lo][k0 + 16] | ((u32)Ls[lo][k0 + 17] << 16);
    o.w = (u32)Ls[lo][k0 + 18] | ((u32)Ls[lo][k0 + 19] << 16);
    dst[(size_t)kc * 64 + l] = o;
  }
}

// pack a row-major [NM x ND] matrix (fp32 or bf16 input), one block per rb
template <bool F32IN>
__global__ __launch_bounds__(256) void pack_a(const void* __restrict__ src,
                                              uint4* __restrict__ dst) {
  __shared__ u16 Ls[16][1032];
  const int rb = blockIdx.x;
  const int t  = threadIdx.x;
  const int row = t >> 4;
  if (F32IN) {
    const float* S = (const float*)src + (size_t)(rb * 16 + row) * ND;
#pragma unroll
    for (int rep = 0; rep < 16; ++rep) {
      int c0 = (t & 15) * 4 + rep * 64;
      float4 v = *(const float4*)(S + c0);
      Ls[row][c0 + 0] = (u16)f2bf(v.x); Ls[row][c0 + 1] = (u16)f2bf(v.y);
      Ls[row][c0 + 2] = (u16)f2bf(v.z); Ls[row][c0 + 3] = (u16)f2bf(v.w);
    }
  } else {
    const u16* S = (const u16*)src + (size_t)(rb * 16 + row) * ND;
#pragma unroll
    for (int rep = 0; rep < 8; ++rep) {
      int c0 = (t & 15) * 8 + rep * 128;
      uint4 v = *(const uint4*)(S + c0);
      u32 a[4] = {v.x, v.y, v.z, v.w};
#pragma unroll
      for (int jj = 0; jj < 4; ++jj) {
        Ls[row][c0 + 2 * jj]     = (u16)(a[jj] & 0xffffu);
        Ls[row][c0 + 2 * jj + 1] = (u16)(a[jj] >> 16);
      }
    }
  }
  __syncthreads();
  pack_emit(Ls, dst + (size_t)rb * 32 * 64, t);
}

// pack W (k x n row-major fp32) as W^T fragments: one block per 16-col slice
__global__ __launch_bounds__(256) void pack_w(const float* __restrict__ W0,
                                              const float* __restrict__ W1,
                                              const float* __restrict__ W2,
                                              uint4* __restrict__ P0,
                                              uint4* __restrict__ P1,
                                              uint4* __restrict__ P2) {
  const float* W = (blockIdx.y == 0) ? W0 : (blockIdx.y == 1) ? W1 : W2;
  uint4* P       = (blockIdx.y == 0) ? P0 : (blockIdx.y == 1) ? P1 : P2;
  __shared__ u16 Ls[16][1032];
  const int n16 = blockIdx.x;
  const int t   = threadIdx.x;
  const int n0  = n16 * 16;
#pragma unroll
  for (int rep = 0; rep < 16; ++rep) {
    int k  = rep * 64 + (t >> 2);
    int c4 = (t & 3) * 4;
    float4 v = *(const float4*)(W + (size_t)k * ND + n0 + c4);
    Ls[c4 + 0][k] = (u16)f2bf(v.x); Ls[c4 + 1][k] = (u16)f2bf(v.y);
    Ls[c4 + 2][k] = (u16)f2bf(v.z); Ls[c4 + 3][k] = (u16)f2bf(v.w);
  }
  __syncthreads();
  pack_emit(Ls, P + (size_t)n16 * 32 * 64, t);
}

// ===========================================================================
// bf16 MFMA GEMM, m97 structure: 128x128 tile, BK=32, 4 waves (2x2),
// global_load_lds staging, ds_read_b128 fragment reads, 16 MFMA / K-step.
// ===========================================================================
template <bool F32OUT>
__device__ __forceinline__ void gemm_mfma_body(const uint4* __restrict__ PA,
                                               const uint4* __restrict__ PB,
                                               void* __restrict__ Cv,
                                               float scale, int bx, int by) {
  __shared__ uint4 As[512];   // 8KB: [m-local 0..7][lane]
  __shared__ uint4 Bs[512];
  const int t  = threadIdx.x;
  const int w  = t >> 6, l = t & 63;
  const int lo = l & 15, hi = l >> 4;
  const int wr = w >> 1, wc = w & 1;

  const uint4* pa0 = PA + ((size_t)(by * 8 + w * 2 + 0) * 32) * 64 + l;
  const uint4* pa1 = PA + ((size_t)(by * 8 + w * 2 + 1) * 32) * 64 + l;
  const uint4* pb0 = PB + ((size_t)(bx * 8 + w * 2 + 0) * 32) * 64 + l;
  const uint4* pb1 = PB + ((size_t)(bx * 8 + w * 2 + 1) * 32) * 64 + l;
  uint4* as0 = &As[(w * 2 + 0) * 64];
  uint4* as1 = &As[(w * 2 + 1) * 64];
  uint4* bs0 = &Bs[(w * 2 + 0) * 64];
  uint4* bs1 = &Bs[(w * 2 + 1) * 64];

  f32x4 acc[4][4];
#pragma unroll
  for (int i = 0; i < 4; ++i)
#pragma unroll
    for (int j = 0; j < 4; ++j) acc[i][j] = (f32x4){0.f, 0.f, 0.f, 0.f};

  for (int kc = 0; kc < 32; ++kc) {
    __syncthreads();                         // prior tile's reads complete
    gload16(pa0 + kc * 64, as0);
    gload16(pa1 + kc * 64, as1);
    gload16(pb0 + kc * 64, bs0);
    gload16(pb1 + kc * 64, bs1);
    __syncthreads();                         // staging complete (vmcnt drained)

    FragU a[4], b[4];
#pragma unroll
    for (int i = 0; i < 4; ++i) *(uint4*)a[i].u = As[(wr * 4 + i) * 64 + l];
#pragma unroll
    for (int j = 0; j < 4; ++j) *(uint4*)b[j].u = Bs[(wc * 4 + j) * 64 + l];
#pragma unroll
    for (int i = 0; i < 4; ++i)
#pragma unroll
      for (int j = 0; j < 4; ++j)
        acc[i][j] = __builtin_amdgcn_mfma_f32_16x16x32_bf16(a[i].v, b[j].v,
                                                            acc[i][j], 0, 0, 0);
  }

  // D layout: row = hi*4 + reg, col = lo (within each 16x16 fragment)
  const int row0 = by * 128 + wr * 64 + hi * 4;
  const int col0 = bx * 128 + wc * 64 + lo;
#pragma unroll
  for (int i = 0; i < 4; ++i)
#pragma unroll
    for (int reg = 0; reg < 4; ++reg) {
      const size_t rbase = (size_t)(row0 + i * 16 + reg) * ND + col0;
      if (F32OUT) {
        float* C = (float*)Cv;
#pragma unroll
        for (int j = 0; j < 4; ++j) C[rbase + j * 16] = acc[i][j][reg] * scale;
      } else {
        u16* C = (u16*)Cv;
#pragma unroll
        for (int j = 0; j < 4; ++j)
          C[rbase + j * 16] = (u16)f2bf(acc[i][j][reg] * scale);
      }
    }
}

__global__ __launch_bounds__(256) void gemm_qkv(const uint4* __restrict__ PA,
                                                const uint4* __restrict__ PWq,
                                                const uint4* __restrict__ PWk,
                                                const uint4* __restrict__ PWv,
                                                u16* __restrict__ Qb,
                                                u16* __restrict__ Kb,
                                                u16* __restrict__ Vb) {
  const uint4* PB;
  u16* C;
  float scale;
  // q scale = 1/sqrt(1024) * log2(e)  (softmax runs in base-2 domain)
  if (blockIdx.z == 0)      { PB = PWq; C = Qb; scale = 0.03125f * 1.44269504f; }
  else if (blockIdx.z == 1) { PB = PWk; C = Kb; scale = 1.f; }
  else                      { PB = PWv; C = Vb; scale = 1.f; }
  gemm_mfma_body<false>(PA, PB, C, scale, blockIdx.x, blockIdx.y);
}

__global__ __launch_bounds__(256) void gemm_out(const uint4* __restrict__ PY,
                                                const uint4* __restrict__ PWo,
                                                float* __restrict__ C) {
  gemm_mfma_body<true>(PY, PWo, C, 1.f, blockIdx.x, blockIdx.y);
}

// ---------------------------------------------------------------------------
// RoPE cos/sin table: tab[l*32+p] = bf16(cos)|bf16(sin)<<16
// ---------------------------------------------------------------------------
__global__ __launch_bounds__(256) void rope_tab(u32* __restrict__ tab) {
  int i = blockIdx.x * 256 + threadIdx.x;      // 0..65535
  int l = i >> 5, p = i & 31;
  float invf = expf(-(float)p * 0.28782313662425572f);   // ln(10000)/32
  float ang = (float)l * invf;
  float sn, cs;
  sincosf(ang, &sn, &cs);
  tab[i] = f2bf(cs) | (f2bf(sn) << 16);
}

// RoPE applied in place to bf16 Q and K (row-major). One thread = 8 bf16.
__global__ __launch_bounds__(256) void rope_apply(u32* __restrict__ Qb,
                                                  u32* __restrict__ Kb,
                                                  const u32* __restrict__ tab) {
  const int PER = NM * (ND / 8);
  int i = blockIdx.x * 256 + threadIdx.x;
  uint4* base = (uint4*)Qb;
  if (i >= PER) { base = (uint4*)Kb; i -= PER; }
  int row = i >> 7;
  int ch  = i & 127;
  int l   = row & (NL - 1);
  int p0  = (ch & 7) * 4;
  uint4 v = base[i];
  const u32* tp = tab + l * 32 + p0;
  u32 vv[4] = {v.x, v.y, v.z, v.w};
  u32 oo[4];
#pragma unroll
  for (int j = 0; j < 4; ++j) {
    u32 cs = tp[j];
    float c = bf2f(cs & 0xffffu), s = bf2f(cs >> 16);
    float x0 = bf2f(vv[j] & 0xffffu), x1 = bf2f(vv[j] >> 16);
    oo[j] = f2bf(x0 * c - x1 * s) | (f2bf(x1 * c + x0 * s) << 16);
  }
  base[i] = make_uint4(oo[0], oo[1], oo[2], oo[3]);
}

// ---------------------------------------------------------------------------
// V transpose: Vb[b,l,h,d] bf16 -> Vt[(b,h), d, l] bf16
// ---------------------------------------------------------------------------
__global__ __launch_bounds__(256) void vtrans(const u16* __restrict__ Vb,
                                              u16* __restrict__ Vt) {
  __shared__ u16 Ls[64][80];
  const int bh = blockIdx.y;
  const int lt = blockIdx.x;
  const int b = bh >> 4, h = bh & 15;
  const int t = threadIdx.x;
  const int l0 = lt * 64;
#pragma unroll
  for (int rep = 0; rep < 2; ++rep) {
    int idx = rep * 256 + t;
    int lrow = idx >> 3, c8 = idx & 7;
    uint4 v = *(const uint4*)(Vb + (size_t)(b * NL + l0 + lrow) * ND + h * 64 + c8 * 8);
    *(uint4*)&Ls[lrow][c8 * 8] = v;
  }
  __syncthreads();
#pragma unroll
  for (int rep = 0; rep < 2; ++rep) {
    int idx = rep * 256 + t;
    int d = idx >> 3, lq = idx & 7;
    u32 wds[4];
#pragma unroll
    for (int jj = 0; jj < 4; ++jj)
      wds[jj] = (u32)Ls[lq * 8 + 2 * jj][d] | ((u32)Ls[lq * 8 + 2 * jj + 1][d] << 16);
    *(uint4*)(Vt + (size_t)(bh * 64 + d) * NL + l0 + lq * 8) =
        make_uint4(wds[0], wds[1], wds[2], wds[3]);
  }
}

// ---------------------------------------------------------------------------
// Causal flash attention, bf16 MFMA (16x16x32), fp32 accum, base-2 softmax.
// (unchanged from round 2 except Y output is now bf16)
// ---------------------------------------------------------------------------
__global__ __launch_bounds__(256, 4) void attn_mfma(
    const u16* __restrict__ Qb,
    const u16* __restrict__ Kb,
    const u16* __restrict__ Vt,
    u16* __restrict__ Y) {
  __shared__ uint4 Ks[512];
  __shared__ uint4 Vs[512];

  const int qt = (int)gridDim.x - 1 - (int)blockIdx.x;   // heavy blocks first
  const int bh = blockIdx.y;
  const int b = bh >> 4, h = bh & 15;
  const int t = threadIdx.x;
  const int w = t >> 6, l = t & 63;
  const int lo = l & 15, hi = l >> 4;
  const int hi4 = hi * 4;

  const int qrow = qt * 64 + w * 16 + lo;
  const char* qc = (const char*)(Qb + ((size_t)(b * NL + qrow)) * ND + h * 64);
  FragU qf[2];
  {
    uint2 a0 = *(const uint2*)(qc + hi * 8);
    uint2 b0 = *(const uint2*)(qc + hi * 8 + 32);
    uint2 a1 = *(const uint2*)(qc + hi * 8 + 64);
    uint2 b1 = *(const uint2*)(qc + hi * 8 + 96);
    qf[0].u[0] = a0.x; qf[0].u[1] = a0.y; qf[0].u[2] = b0.x; qf[0].u[3] = b0.y;
    qf[1].u[0] = a1.x; qf[1].u[1] = a1.y; qf[1].u[2] = b1.x; qf[1].u[3] = b1.y;
  }

  const char* kbase = (const char*)(Kb + (size_t)b * NL * ND + h * 64);
  const char* vbase = (const char*)(Vt + (size_t)bh * 64 * NL);
  const char* pK[2];
  const char* pV[2];
  int cid[2];
#pragma unroll
  for (int r = 0; r < 2; ++r) {
    int c = r * 256 + t;
    cid[r] = c;
    int lc = c & 63;
    int pair = c >> 6;
    int g16 = pair >> 1;
    int c32 = pair & 1;
    int row = g16 * 16 + (lc & 15);
    int offA = c32 * 64 + ((lc >> 4) << 3);
    pK[r] = kbase + (size_t)row * (ND * 2) + offA;
    pV[r] = vbase + (size_t)row * (NL * 2) + offA;
  }

  f32x4 yacc[4];
#pragma unroll
  for (int et = 0; et < 4; ++et) yacc[et] = (f32x4){0.f, 0.f, 0.f, 0.f};
  float m_run = -1e30f, l_run = 0.f;

  for (int kt = 0; kt <= qt; ++kt) {
    __syncthreads();
#pragma unroll
    for (int r = 0; r < 2; ++r) {
      const char* sk = pK[r] + (size_t)kt * (64 * ND * 2);
      uint2 ka = *(const uint2*)sk;
      uint2 kb2 = *(const uint2*)(sk + 32);
      Ks[cid[r]] = make_uint4(ka.x, ka.y, kb2.x, kb2.y);
      const char* sv = pV[r] + (size_t)kt * 128;
      uint2 va = *(const uint2*)sv;
      uint2 vb2 = *(const uint2*)(sv + 32);
      Vs[cid[r]] = make_uint4(va.x, va.y, vb2.x, vb2.y);
    }
    __syncthreads();

    f32x4 sacc[4];
#pragma unroll
    for (int kg = 0; kg < 4; ++kg) {
      sacc[kg] = (f32x4){0.f, 0.f, 0.f, 0.f};
#pragma unroll
      for (int c32 = 0; c32 < 2; ++c32) {
        FragU kf;
        *(uint4*)kf.u = Ks[(kg * 2 + c32) * 64 + l];
        sacc[kg] = __builtin_amdgcn_mfma_f32_16x16x32_bf16(kf.v, qf[c32].v,
                                                           sacc[kg], 0, 0, 0);
      }
    }

    if (kt == qt) {
#pragma unroll
      for (int kg = 0; kg < 4; ++kg)
#pragma unroll
        for (int reg = 0; reg < 4; ++reg) {
          int key = kt * 64 + kg * 16 + hi4 + reg;
          if (key > qrow) sacc[kg][reg] = -1e30f;
        }
    }

    float mt = sacc[0][0];
#pragma unroll
    for (int kg = 0; kg < 4; ++kg)
#pragma unroll
      for (int reg = 0; reg < 4; ++reg) mt = fmaxf(mt, sacc[kg][reg]);
    mt = fmaxf(mt, __shfl_xor(mt, 16));
    mt = fmaxf(mt, __shfl_xor(mt, 32));
    float mnew = fmaxf(m_run, mt);
    float corr = exp2f(m_run - mnew);
    float ps = 0.f;
#pragma unroll
    for (int kg = 0; kg < 4; ++kg)
#pragma unroll
      for (int reg = 0; reg < 4; ++reg) {
        float e = exp2f(sacc[kg][reg] - mnew);
        sacc[kg][reg] = e;
        ps += e;
      }
    ps += __shfl_xor(ps, 16);
    ps += __shfl_xor(ps, 32);
    l_run = l_run * corr + ps;
    m_run = mnew;

    float c0 = __shfl(corr, hi4 + 0);
    float c1 = __shfl(corr, hi4 + 1);
    float c2 = __shfl(corr, hi4 + 2);
    float c3 = __shfl(corr, hi4 + 3);
#pragma unroll
    for (int et = 0; et < 4; ++et) {
      yacc[et][0] *= c0; yacc[et][1] *= c1;
      yacc[et][2] *= c2; yacc[et][3] *= c3;
    }

    FragU pa0, pa1;
    pa0.u[0] = f2bf(sacc[0][0]) | (f2bf(sacc[0][1]) << 16);
    pa0.u[1] = f2bf(sacc[0][2]) | (f2bf(sacc[0][3]) << 16);
    pa0.u[2] = f2bf(sacc[1][0]) | (f2bf(sacc[1][1]) << 16);
    pa0.u[3] = f2bf(sacc[1][2]) | (f2bf(sacc[1][3]) << 16);
    pa1.u[0] = f2bf(sacc[2][0]) | (f2bf(sacc[2][1]) << 16);
    pa1.u[1] = f2bf(sacc[2][2]) | (f2bf(sacc[2][3]) << 16);
    pa1.u[2] = f2bf(sacc[3][0]) | (f2bf(sacc[3][1]) << 16);
    pa1.u[3] = f2bf(sacc[3][2]) | (f2bf(sacc[3][3]) << 16);

#pragma unroll
    for (int et = 0; et < 4; ++et) {
      FragU vf0, vf1;
      *(uint4*)vf0.u = Vs[(et * 2 + 0) * 64 + l];
      *(uint4*)vf1.u = Vs[(et * 2 + 1) * 64 + l];
      yacc[et] = __builtin_amdgcn_mfma_f32_16x16x32_bf16(pa0.v, vf0.v, yacc[et], 0, 0, 0);
      yacc[et] = __builtin_amdgcn_mfma_f32_16x16x32_bf16(pa1.v, vf1.v, yacc[et], 0, 0, 0);
    }
  }

  float li0 = 1.f / __shfl(l_run, hi4 + 0);
  float li1 = 1.f / __shfl(l_run, hi4 + 1);
  float li2 = 1.f / __shfl(l_run, hi4 + 2);
  float li3 = 1.f / __shfl(l_run, hi4 + 3);
  const size_t ybase = (size_t)(b * NL + qt * 64 + w * 16) * ND + h * 64;
#pragma unroll
  for (int et = 0; et < 4; ++et) {
    Y[ybase + (size_t)(hi4 + 0) * ND + et * 16 + lo] = (u16)f2bf(yacc[et][0] * li0);
    Y[ybase + (size_t)(hi4 + 1) * ND + et * 16 + lo] = (u16)f2bf(yacc[et][1] * li1);
    Y[ybase + (size_t)(hi4 + 2) * ND + et * 16 + lo] = (u16)f2bf(yacc[et][2] * li2);
    Y[ybase + (size_t)(hi4 + 3) * ND + et * 16 + lo] = (u16)f2bf(yacc[et][3] * li3);
  }
}

// ---------------------------------------------------------------------------
extern "C" void kernel_launch(void* const* d_in, const int* in_sizes, int n_in,
                              void* d_out, int out_size, void* d_ws,
                              size_t ws_size, hipStream_t stream) {
  const float* x  = (const float*)d_in[0];
  const float* Wq = (const float*)d_in[1];
  const float* Wk = (const float*)d_in[2];
  const float* Wv = (const float*)d_in[3];
  const float* Wo = (const float*)d_in[4];
  float* out = (float*)d_out;

  // workspace layout (46.25 MB):
  //   [0,8)    Qb row-major bf16          -> reused for PWo after attn
  //   [8,16)   Kb row-major bf16
  //   [16,24)  Vb row-major bf16          -> reused as Yb after vtrans
  //   [24,32)  Vt bf16
  //   [32,40)  PA packed x                -> reused as PY after gemm_qkv
  //   [40,46)  PWq | PWk | PWv (2MB each)
  //   [46,46.25) rope tab
  char* ws = (char*)d_ws;
  u16*   Qb  = (u16*)(ws);
  u16*   Kb  = (u16*)(ws + ((size_t)8 << 20));
  u16*   Vb  = (u16*)(ws + ((size_t)16 << 20));
  u16*   Yb  = Vb;
  u16*   Vt  = (u16*)(ws + ((size_t)24 << 20));
  uint4* PA  = (uint4*)(ws + ((size_t)32 << 20));
  uint4* PY  = PA;
  uint4* PWq = (uint4*)(ws + ((size_t)40 << 20));
  uint4* PWk = (uint4*)(ws + ((size_t)42 << 20));
  uint4* PWv = (uint4*)(ws + ((size_t)44 << 20));
  uint4* PWo = (uint4*)Qb;
  u32*   tab = (u32*)(ws + ((size_t)46 << 20));

  dim3 blk(256);

  pack_w<<<dim3(64, 3), blk, 0, stream>>>(Wq, Wk, Wv, PWq, PWk, PWv);
  pack_a<true><<<dim3(NM / 16), blk, 0, stream>>>(x, PA);
  gemm_qkv<<<dim3(8, 32, 3), blk, 0, stream>>>(PA, PWq, PWk, PWv, Qb, Kb, Vb);
  rope_tab<<<dim3(NL * 32 / 256), blk, 0, stream>>>(tab);
  rope_apply<<<dim3(2 * NM * (ND / 8) / 256), blk, 0, stream>>>(
      (u32*)Qb, (u32*)Kb, tab);
  vtrans<<<dim3(NL / 64, NB * NH), blk, 0, stream>>>(Vb, Vt);
  attn_mfma<<<dim3(NL / 64, NB * NH), blk, 0, stream>>>(Qb, Kb, Vt, Yb);
  pack_a<false><<<dim3(NM / 16), blk, 0, stream>>>(Yb, PY);
  pack_w<<<dim3(64, 1), blk, 0, stream>>>(Wo, Wo, Wo, PWo, PWo, PWo);
  gemm_out<<<dim3(8, 32), blk, 0, stream>>>(PY, PWo, out);
}

// Round 4
// 157.225 us; speedup vs baseline: 37.5905x; 1.4355x over previous
//
#include <hip/hip_runtime.h>
#include <hip/hip_bf16.h>
#include <math.h>

#define NB 2
#define NL 2048
#define ND 1024
#define NH 16
#define NDH 64
#define NM (NB * NL)   // 4096 rows

typedef __bf16 bf16x8 __attribute__((ext_vector_type(8)));
typedef float  f32x4  __attribute__((ext_vector_type(4)));
typedef unsigned int   u32;
typedef unsigned short u16;

union FragU { u32 u[4]; bf16x8 v; };

__device__ __forceinline__ u32 f2bf(float f) {   // RTNE f32 -> bf16 bits
  u32 u = __float_as_uint(f);
  return (u + 0x7fffu + ((u >> 16) & 1u)) >> 16;
}
__device__ __forceinline__ float bf2f(u32 b) { return __uint_as_float(b << 16); }

// async global->LDS, 16B per lane; LDS dest wave-uniform base + lane*16
__device__ __forceinline__ void gload16(const void* g, void* l) {
  __builtin_amdgcn_global_load_lds(
      (const __attribute__((address_space(1))) u32*)g,
      (__attribute__((address_space(3))) u32*)l, 16, 0, 0);
}

// ===========================================================================
// Packed operand layout:
//   P[rb][kc][lane] : 16B chunk, rb = 16-row block, kc = 32-col(k) chunk
//   chunk(rb,kc,l) = { src[16rb+(l&15)][32kc+4(l>>4)+0..3],
//                      src[16rb+(l>>4? same)+16+4(l>>4)+0..3] }  (bf16)
// One lane's A-frag (rows) / B-frag (cols) for mfma_f32_16x16x32_bf16.
// ===========================================================================

// shared emit phase: Ls[16][1032] bf16 -> 32 kc * 64 lane chunks
__device__ __forceinline__ void pack_emit(const u16 Ls[16][1032],
                                          uint4* __restrict__ dst, int t) {
#pragma unroll
  for (int rep = 0; rep < 8; ++rep) {
    int c  = rep * 256 + t;          // 0..2047
    int kc = c >> 6, l = c & 63;
    int lo = l & 15, hi = l >> 4;
    int k0 = kc * 32 + hi * 4;
    uint4 o;
    o.x = (u32)Ls[lo][k0 + 0]  | ((u32)Ls[lo][k0 + 1]  << 16);
    o.y = (u32)Ls[lo][k0 + 2]  | ((u32)Ls[lo][k0 + 3]  << 16);
    o.z = (u32)Ls[lo][k0 + 16] | ((u32)Ls[lo][k0 + 17] << 16);
    o.w = (u32)Ls[lo][k0 + 18] | ((u32)Ls[lo][k0 + 19] << 16);
    dst[(size_t)kc * 64 + l] = o;
  }
}

// pack a row-major [NM x ND] matrix (fp32 or bf16 input), one block per rb
template <bool F32IN>
__global__ __launch_bounds__(256) void pack_a(const void* __restrict__ src,
                                              uint4* __restrict__ dst) {
  __shared__ u16 Ls[16][1032];
  const int rb = blockIdx.x;
  const int t  = threadIdx.x;
  const int row = t >> 4;
  if (F32IN) {
    const float* S = (const float*)src + (size_t)(rb * 16 + row) * ND;
#pragma unroll
    for (int rep = 0; rep < 16; ++rep) {
      int c0 = (t & 15) * 4 + rep * 64;
      float4 v = *(const float4*)(S + c0);
      Ls[row][c0 + 0] = (u16)f2bf(v.x); Ls[row][c0 + 1] = (u16)f2bf(v.y);
      Ls[row][c0 + 2] = (u16)f2bf(v.z); Ls[row][c0 + 3] = (u16)f2bf(v.w);
    }
  } else {
    const u16* S = (const u16*)src + (size_t)(rb * 16 + row) * ND;
#pragma unroll
    for (int rep = 0; rep < 8; ++rep) {
      int c0 = (t & 15) * 8 + rep * 128;
      uint4 v = *(const uint4*)(S + c0);
      u32 a[4] = {v.x, v.y, v.z, v.w};
#pragma unroll
      for (int jj = 0; jj < 4; ++jj) {
        Ls[row][c0 + 2 * jj]     = (u16)(a[jj] & 0xffffu);
        Ls[row][c0 + 2 * jj + 1] = (u16)(a[jj] >> 16);
      }
    }
  }
  __syncthreads();
  pack_emit(Ls, dst + (size_t)rb * 32 * 64, t);
}

// pack W (k x n row-major fp32) as W^T fragments: one block per 16-col slice
__global__ __launch_bounds__(256) void pack_w(const float* __restrict__ W0,
                                              const float* __restrict__ W1,
                                              const float* __restrict__ W2,
                                              uint4* __restrict__ P0,
                                              uint4* __restrict__ P1,
                                              uint4* __restrict__ P2) {
  const float* W = (blockIdx.y == 0) ? W0 : (blockIdx.y == 1) ? W1 : W2;
  uint4* P       = (blockIdx.y == 0) ? P0 : (blockIdx.y == 1) ? P1 : P2;
  __shared__ u16 Ls[16][1032];
  const int n16 = blockIdx.x;
  const int t   = threadIdx.x;
  const int n0  = n16 * 16;
#pragma unroll
  for (int rep = 0; rep < 16; ++rep) {
    int k  = rep * 64 + (t >> 2);
    int c4 = (t & 3) * 4;
    float4 v = *(const float4*)(W + (size_t)k * ND + n0 + c4);
    Ls[c4 + 0][k] = (u16)f2bf(v.x); Ls[c4 + 1][k] = (u16)f2bf(v.y);
    Ls[c4 + 2][k] = (u16)f2bf(v.z); Ls[c4 + 3][k] = (u16)f2bf(v.w);
  }
  __syncthreads();
  pack_emit(Ls, P + (size_t)n16 * 32 * 64, t);
}

// ===========================================================================
// bf16 MFMA GEMM, m97 structure: 128x128 tile, BK=32, 4 waves (2x2),
// global_load_lds staging, ds_read_b128 fragment reads, 16 MFMA / K-step.
// ===========================================================================
template <bool F32OUT>
__device__ __forceinline__ void gemm_mfma_body(const uint4* __restrict__ PA,
                                               const uint4* __restrict__ PB,
                                               void* __restrict__ Cv,
                                               float scale, int bx, int by) {
  __shared__ uint4 As[512];   // 8KB: [m-local 0..7][lane]
  __shared__ uint4 Bs[512];
  const int t  = threadIdx.x;
  const int w  = t >> 6, l = t & 63;
  const int lo = l & 15, hi = l >> 4;
  const int wr = w >> 1, wc = w & 1;

  const uint4* pa0 = PA + ((size_t)(by * 8 + w * 2 + 0) * 32) * 64 + l;
  const uint4* pa1 = PA + ((size_t)(by * 8 + w * 2 + 1) * 32) * 64 + l;
  const uint4* pb0 = PB + ((size_t)(bx * 8 + w * 2 + 0) * 32) * 64 + l;
  const uint4* pb1 = PB + ((size_t)(bx * 8 + w * 2 + 1) * 32) * 64 + l;
  uint4* as0 = &As[(w * 2 + 0) * 64];
  uint4* as1 = &As[(w * 2 + 1) * 64];
  uint4* bs0 = &Bs[(w * 2 + 0) * 64];
  uint4* bs1 = &Bs[(w * 2 + 1) * 64];

  f32x4 acc[4][4];
#pragma unroll
  for (int i = 0; i < 4; ++i)
#pragma unroll
    for (int j = 0; j < 4; ++j) acc[i][j] = (f32x4){0.f, 0.f, 0.f, 0.f};

  for (int kc = 0; kc < 32; ++kc) {
    __syncthreads();                         // prior tile's reads complete
    gload16(pa0 + kc * 64, as0);
    gload16(pa1 + kc * 64, as1);
    gload16(pb0 + kc * 64, bs0);
    gload16(pb1 + kc * 64, bs1);
    __syncthreads();                         // staging complete (vmcnt drained)

    FragU a[4], b[4];
#pragma unroll
    for (int i = 0; i < 4; ++i) *(uint4*)a[i].u = As[(wr * 4 + i) * 64 + l];
#pragma unroll
    for (int j = 0; j < 4; ++j) *(uint4*)b[j].u = Bs[(wc * 4 + j) * 64 + l];
#pragma unroll
    for (int i = 0; i < 4; ++i)
#pragma unroll
      for (int j = 0; j < 4; ++j)
        acc[i][j] = __builtin_amdgcn_mfma_f32_16x16x32_bf16(a[i].v, b[j].v,
                                                            acc[i][j], 0, 0, 0);
  }

  // D layout: row = hi*4 + reg, col = lo (within each 16x16 fragment)
  const int row0 = by * 128 + wr * 64 + hi * 4;
  const int col0 = bx * 128 + wc * 64 + lo;
#pragma unroll
  for (int i = 0; i < 4; ++i)
#pragma unroll
    for (int reg = 0; reg < 4; ++reg) {
      const size_t rbase = (size_t)(row0 + i * 16 + reg) * ND + col0;
      if (F32OUT) {
        float* C = (float*)Cv;
#pragma unroll
        for (int j = 0; j < 4; ++j) C[rbase + j * 16] = acc[i][j][reg] * scale;
      } else {
        u16* C = (u16*)Cv;
#pragma unroll
        for (int j = 0; j < 4; ++j)
          C[rbase + j * 16] = (u16)f2bf(acc[i][j][reg] * scale);
      }
    }
}

__global__ __launch_bounds__(256) void gemm_qkv(const uint4* __restrict__ PA,
                                                const uint4* __restrict__ PWq,
                                                const uint4* __restrict__ PWk,
                                                const uint4* __restrict__ PWv,
                                                u16* __restrict__ Qb,
                                                u16* __restrict__ Kb,
                                                u16* __restrict__ Vb) {
  const uint4* PB;
  u16* C;
  float scale;
  // q scale = 1/sqrt(1024) * log2(e)  (softmax runs in base-2 domain)
  if (blockIdx.z == 0)      { PB = PWq; C = Qb; scale = 0.03125f * 1.44269504f; }
  else if (blockIdx.z == 1) { PB = PWk; C = Kb; scale = 1.f; }
  else                      { PB = PWv; C = Vb; scale = 1.f; }
  gemm_mfma_body<false>(PA, PB, C, scale, blockIdx.x, blockIdx.y);
}

__global__ __launch_bounds__(256) void gemm_out(const uint4* __restrict__ PY,
                                                const uint4* __restrict__ PWo,
                                                float* __restrict__ C) {
  gemm_mfma_body<true>(PY, PWo, C, 1.f, blockIdx.x, blockIdx.y);
}

// ---------------------------------------------------------------------------
// RoPE cos/sin table: tab[l*32+p] = bf16(cos)|bf16(sin)<<16
// ---------------------------------------------------------------------------
__global__ __launch_bounds__(256) void rope_tab(u32* __restrict__ tab) {
  int i = blockIdx.x * 256 + threadIdx.x;      // 0..65535
  int l = i >> 5, p = i & 31;
  float invf = expf(-(float)p * 0.28782313662425572f);   // ln(10000)/32
  float ang = (float)l * invf;
  float sn, cs;
  sincosf(ang, &sn, &cs);
  tab[i] = f2bf(cs) | (f2bf(sn) << 16);
}

// RoPE applied in place to bf16 Q and K (row-major). One thread = 8 bf16.
__global__ __launch_bounds__(256) void rope_apply(u32* __restrict__ Qb,
                                                  u32* __restrict__ Kb,
                                                  const u32* __restrict__ tab) {
  const int PER = NM * (ND / 8);
  int i = blockIdx.x * 256 + threadIdx.x;
  uint4* base = (uint4*)Qb;
  if (i >= PER) { base = (uint4*)Kb; i -= PER; }
  int row = i >> 7;
  int ch  = i & 127;
  int l   = row & (NL - 1);
  int p0  = (ch & 7) * 4;
  uint4 v = base[i];
  const u32* tp = tab + l * 32 + p0;
  u32 vv[4] = {v.x, v.y, v.z, v.w};
  u32 oo[4];
#pragma unroll
  for (int j = 0; j < 4; ++j) {
    u32 cs = tp[j];
    float c = bf2f(cs & 0xffffu), s = bf2f(cs >> 16);
    float x0 = bf2f(vv[j] & 0xffffu), x1 = bf2f(vv[j] >> 16);
    oo[j] = f2bf(x0 * c - x1 * s) | (f2bf(x1 * c + x0 * s) << 16);
  }
  base[i] = make_uint4(oo[0], oo[1], oo[2], oo[3]);
}

// ---------------------------------------------------------------------------
// V transpose: Vb[b,l,h,d] bf16 -> Vt[(b,h), d, l] bf16
// ---------------------------------------------------------------------------
__global__ __launch_bounds__(256) void vtrans(const u16* __restrict__ Vb,
                                              u16* __restrict__ Vt) {
  __shared__ u16 Ls[64][80];
  const int bh = blockIdx.y;
  const int lt = blockIdx.x;
  const int b = bh >> 4, h = bh & 15;
  const int t = threadIdx.x;
  const int l0 = lt * 64;
#pragma unroll
  for (int rep = 0; rep < 2; ++rep) {
    int idx = rep * 256 + t;
    int lrow = idx >> 3, c8 = idx & 7;
    uint4 v = *(const uint4*)(Vb + (size_t)(b * NL + l0 + lrow) * ND + h * 64 + c8 * 8);
    *(uint4*)&Ls[lrow][c8 * 8] = v;
  }
  __syncthreads();
#pragma unroll
  for (int rep = 0; rep < 2; ++rep) {
    int idx = rep * 256 + t;
    int d = idx >> 3, lq = idx & 7;
    u32 wds[4];
#pragma unroll
    for (int jj = 0; jj < 4; ++jj)
      wds[jj] = (u32)Ls[lq * 8 + 2 * jj][d] | ((u32)Ls[lq * 8 + 2 * jj + 1][d] << 16);
    *(uint4*)(Vt + (size_t)(bh * 64 + d) * NL + l0 + lq * 8) =
        make_uint4(wds[0], wds[1], wds[2], wds[3]);
  }
}

// ---------------------------------------------------------------------------
// Online softmax (base 2) for one 32-key x 16-row S block held as s[4] f32x4.
// Rows live at lane lo; yacc rows at hi4+reg -> corr broadcast via 4 shfl.
// Emits P as two A-fragments (keys 0..31, 32..63).
// ---------------------------------------------------------------------------
__device__ __forceinline__ void online_sm(f32x4* s, float& m_run, float& l_run,
                                          f32x4* y, int hi4,
                                          FragU& pa0, FragU& pa1) {
  float mt = s[0][0];
#pragma unroll
  for (int kg = 0; kg < 4; ++kg)
#pragma unroll
    for (int reg = 0; reg < 4; ++reg) mt = fmaxf(mt, s[kg][reg]);
  mt = fmaxf(mt, __shfl_xor(mt, 16));
  mt = fmaxf(mt, __shfl_xor(mt, 32));
  const float mnew = fmaxf(m_run, mt);
  const float corr = exp2f(m_run - mnew);
  float ps = 0.f;
#pragma unroll
  for (int kg = 0; kg < 4; ++kg)
#pragma unroll
    for (int reg = 0; reg < 4; ++reg) {
      float e = exp2f(s[kg][reg] - mnew);
      s[kg][reg] = e;
      ps += e;
    }
  ps += __shfl_xor(ps, 16);
  ps += __shfl_xor(ps, 32);
  l_run = l_run * corr + ps;
  m_run = mnew;

  const float c0 = __shfl(corr, hi4 + 0);
  const float c1 = __shfl(corr, hi4 + 1);
  const float c2 = __shfl(corr, hi4 + 2);
  const float c3 = __shfl(corr, hi4 + 3);
#pragma unroll
  for (int et = 0; et < 4; ++et) {
    y[et][0] *= c0; y[et][1] *= c1; y[et][2] *= c2; y[et][3] *= c3;
  }

  pa0.u[0] = f2bf(s[0][0]) | (f2bf(s[0][1]) << 16);
  pa0.u[1] = f2bf(s[0][2]) | (f2bf(s[0][3]) << 16);
  pa0.u[2] = f2bf(s[1][0]) | (f2bf(s[1][1]) << 16);
  pa0.u[3] = f2bf(s[1][2]) | (f2bf(s[1][3]) << 16);
  pa1.u[0] = f2bf(s[2][0]) | (f2bf(s[2][1]) << 16);
  pa1.u[1] = f2bf(s[2][2]) | (f2bf(s[2][3]) << 16);
  pa1.u[2] = f2bf(s[3][0]) | (f2bf(s[3][1]) << 16);
  pa1.u[3] = f2bf(s[3][2]) | (f2bf(s[3][3]) << 16);
}

__device__ __forceinline__ void attn_store(u16* __restrict__ Y, int rowbase,
                                           int h, const f32x4* y, float l_run,
                                           int lo, int hi4) {
  const float li0 = 1.f / __shfl(l_run, hi4 + 0);
  const float li1 = 1.f / __shfl(l_run, hi4 + 1);
  const float li2 = 1.f / __shfl(l_run, hi4 + 2);
  const float li3 = 1.f / __shfl(l_run, hi4 + 3);
  const size_t ybase = (size_t)rowbase * ND + h * 64;
#pragma unroll
  for (int et = 0; et < 4; ++et) {
    Y[ybase + (size_t)(hi4 + 0) * ND + et * 16 + lo] = (u16)f2bf(y[et][0] * li0);
    Y[ybase + (size_t)(hi4 + 1) * ND + et * 16 + lo] = (u16)f2bf(y[et][1] * li1);
    Y[ybase + (size_t)(hi4 + 2) * ND + et * 16 + lo] = (u16)f2bf(y[et][2] * li2);
    Y[ybase + (size_t)(hi4 + 3) * ND + et * 16 + lo] = (u16)f2bf(y[et][3] * li3);
  }
}

// ---------------------------------------------------------------------------
// Causal flash attention v2: bf16 MFMA, base-2 online softmax.
// Fold-balanced: block (fi, bh) processes q-tiles qt=fi and qt=15-fi
// (QBLK=128: 4 waves x 32 rows), always 34 KV-tile iterations total.
// Double-buffered LDS (16KB x2) with register prefetch (T14 split):
//   [barrier] -> issue loads(kt+1) -> compute from LDS[cur] -> write LDS[cur^1]
// One barrier per iteration; load latency hides under S/softmax/PV.
// ---------------------------------------------------------------------------
__global__ __launch_bounds__(256, 1) void attn_mfma2(
    const u16* __restrict__ Qb,
    const u16* __restrict__ Kb,
    const u16* __restrict__ Vt,
    u16* __restrict__ Y) {
  __shared__ uint4 Ks2[2][512];   // 16KB: [buf][ (kg*2+c32)*64 + lane ]
  __shared__ uint4 Vs2[2][512];   // 16KB: [buf][ (et*2+c32)*64 + lane ]

  const int fi = blockIdx.x;           // 0..7
  const int bh = blockIdx.y;           // 0..31
  const int b = bh >> 4, h = bh & 15;
  const int t = threadIdx.x;
  const int w = t >> 6, l = t & 63;
  const int lo = l & 15, hi = l >> 4;
  const int hi4 = hi * 4;

  // ---- staging decode (per thread: 2 K chunks + 2 V chunks per tile)
  const char* kbase = (const char*)(Kb + (size_t)b * NL * ND + h * 64);
  const char* vbase = (const char*)(Vt + (size_t)bh * 64 * NL);
  const char* pK[2];
  const char* pV[2];
  int cid[2];
#pragma unroll
  for (int r = 0; r < 2; ++r) {
    int c = r * 256 + t;                 // 0..511
    cid[r] = c;
    int lc = c & 63;
    int pair = c >> 6;                   // 0..7
    int g16 = pair >> 1;
    int c32 = pair & 1;
    int row = g16 * 16 + (lc & 15);
    int offA = c32 * 64 + ((lc >> 4) << 3);
    pK[r] = kbase + (size_t)row * (ND * 2) + offA;
    pV[r] = vbase + (size_t)row * (NL * 2) + offA;
  }
  const size_t KTS = (size_t)64 * ND * 2;   // K tile byte stride
  const size_t VTS = 128;                   // V tile byte stride

  // ---- prologue: stage tile 0 into buffer 0
#pragma unroll
  for (int r = 0; r < 2; ++r) {
    uint2 a = *(const uint2*)pK[r];
    uint2 b2 = *(const uint2*)(pK[r] + 32);
    Ks2[0][cid[r]] = make_uint4(a.x, a.y, b2.x, b2.y);
    uint2 c = *(const uint2*)pV[r];
    uint2 d2 = *(const uint2*)(pV[r] + 32);
    Vs2[0][cid[r]] = make_uint4(c.x, c.y, d2.x, d2.y);
  }
  int cur = 0;

  for (int ph = 0; ph < 2; ++ph) {
    const int qt = ph ? (15 - fi) : fi;
    const int nkt = 2 * qt + 2;

    // Q B-fragments for both row groups (rows qt*128 + w*32 + rg*16 + lo)
    FragU qf0[2], qf1[2];
    {
      const char* qc0 = (const char*)(Qb +
          ((size_t)(b * NL + qt * 128 + w * 32 + lo)) * ND + h * 64);
      const char* qc1 = qc0 + (size_t)16 * ND * 2;
      uint2 a0 = *(const uint2*)(qc0 + hi * 8);
      uint2 b0 = *(const uint2*)(qc0 + hi * 8 + 32);
      uint2 a1 = *(const uint2*)(qc0 + hi * 8 + 64);
      uint2 b1 = *(const uint2*)(qc0 + hi * 8 + 96);
      qf0[0].u[0] = a0.x; qf0[0].u[1] = a0.y; qf0[0].u[2] = b0.x; qf0[0].u[3] = b0.y;
      qf0[1].u[0] = a1.x; qf0[1].u[1] = a1.y; qf0[1].u[2] = b1.x; qf0[1].u[3] = b1.y;
      uint2 a2 = *(const uint2*)(qc1 + hi * 8);
      uint2 b2 = *(const uint2*)(qc1 + hi * 8 + 32);
      uint2 a3 = *(const uint2*)(qc1 + hi * 8 + 64);
      uint2 b3 = *(const uint2*)(qc1 + hi * 8 + 96);
      qf1[0].u[0] = a2.x; qf1[0].u[1] = a2.y; qf1[0].u[2] = b2.x; qf1[0].u[3] = b2.y;
      qf1[1].u[0] = a3.x; qf1[1].u[1] = a3.y; qf1[1].u[2] = b3.x; qf1[1].u[3] = b3.y;
    }

    float m0 = -1e30f, l0s = 0.f, m1 = -1e30f, l1s = 0.f;
    f32x4 y0[4], y1[4];
#pragma unroll
    for (int et = 0; et < 4; ++et) {
      y0[et] = (f32x4){0.f, 0.f, 0.f, 0.f};
      y1[et] = (f32x4){0.f, 0.f, 0.f, 0.f};
    }

    for (int kt = 0; kt < nkt; ++kt) {
      __syncthreads();   // LDS[cur] staged & all prior reads of LDS[cur^1] done

      // ---- prefetch next tile into registers (seam -> tile 0 of phase B)
      int ktn = (kt + 1 < nkt) ? kt + 1 : (ph == 0 ? 0 : kt);
      uint4 nk[2], nv[2];
#pragma unroll
      for (int r = 0; r < 2; ++r) {
        const char* sk = pK[r] + (size_t)ktn * KTS;
        uint2 a = *(const uint2*)sk;
        uint2 b2 = *(const uint2*)(sk + 32);
        nk[r] = make_uint4(a.x, a.y, b2.x, b2.y);
        const char* sv = pV[r] + (size_t)ktn * VTS;
        uint2 c = *(const uint2*)sv;
        uint2 d2 = *(const uint2*)(sv + 32);
        nv[r] = make_uint4(c.x, c.y, d2.x, d2.y);
      }

      // ---- S^T = K * Q^T for both row groups (K-frags read once, reused)
      f32x4 s0[4], s1[4];
#pragma unroll
      for (int kg = 0; kg < 4; ++kg) {
        s0[kg] = (f32x4){0.f, 0.f, 0.f, 0.f};
        s1[kg] = (f32x4){0.f, 0.f, 0.f, 0.f};
#pragma unroll
        for (int c32 = 0; c32 < 2; ++c32) {
          FragU kf;
          *(uint4*)kf.u = Ks2[cur][(kg * 2 + c32) * 64 + l];
          s0[kg] = __builtin_amdgcn_mfma_f32_16x16x32_bf16(kf.v, qf0[c32].v,
                                                           s0[kg], 0, 0, 0);
          s1[kg] = __builtin_amdgcn_mfma_f32_16x16x32_bf16(kf.v, qf1[c32].v,
                                                           s1[kg], 0, 0, 0);
        }
      }

      // ---- causal mask (only the last two tiles of a phase cross the diag)
      if (kt >= 2 * qt) {
        const int qr0 = qt * 128 + w * 32 + lo;
#pragma unroll
        for (int kg = 0; kg < 4; ++kg)
#pragma unroll
          for (int reg = 0; reg < 4; ++reg) {
            int key = kt * 64 + kg * 16 + hi4 + reg;
            if (key > qr0)      s0[kg][reg] = -1e30f;
            if (key > qr0 + 16) s1[kg][reg] = -1e30f;
          }
      }

      // ---- online softmax + P fragments
      FragU p00, p01, p10, p11;
      online_sm(s0, m0, l0s, y0, hi4, p00, p01);
      online_sm(s1, m1, l1s, y1, hi4, p10, p11);

      // ---- PV (V-frags read once, reused by both row groups)
#pragma unroll
      for (int et = 0; et < 4; ++et) {
        FragU vf0, vf1;
        *(uint4*)vf0.u = Vs2[cur][(et * 2 + 0) * 64 + l];
        *(uint4*)vf1.u = Vs2[cur][(et * 2 + 1) * 64 + l];
        y0[et] = __builtin_amdgcn_mfma_f32_16x16x32_bf16(p00.v, vf0.v, y0[et], 0, 0, 0);
        y0[et] = __builtin_amdgcn_mfma_f32_16x16x32_bf16(p01.v, vf1.v, y0[et], 0, 0, 0);
        y1[et] = __builtin_amdgcn_mfma_f32_16x16x32_bf16(p10.v, vf0.v, y1[et], 0, 0, 0);
        y1[et] = __builtin_amdgcn_mfma_f32_16x16x32_bf16(p11.v, vf1.v, y1[et], 0, 0, 0);
      }

      // ---- write prefetched tile to the other buffer
#pragma unroll
      for (int r = 0; r < 2; ++r) {
        Ks2[cur ^ 1][cid[r]] = nk[r];
        Vs2[cur ^ 1][cid[r]] = nv[r];
      }
      cur ^= 1;
    }

    // ---- phase epilogue
    attn_store(Y, b * NL + qt * 128 + w * 32,      h, y0, l0s, lo, hi4);
    attn_store(Y, b * NL + qt * 128 + w * 32 + 16, h, y1, l1s, lo, hi4);
  }
}

// ---------------------------------------------------------------------------
extern "C" void kernel_launch(void* const* d_in, const int* in_sizes, int n_in,
                              void* d_out, int out_size, void* d_ws,
                              size_t ws_size, hipStream_t stream) {
  const float* x  = (const float*)d_in[0];
  const float* Wq = (const float*)d_in[1];
  const float* Wk = (const float*)d_in[2];
  const float* Wv = (const float*)d_in[3];
  const float* Wo = (const float*)d_in[4];
  float* out = (float*)d_out;

  // workspace layout (46.25 MB):
  //   [0,8)    Qb row-major bf16          -> reused for PWo after attn
  //   [8,16)   Kb row-major bf16
  //   [16,24)  Vb row-major bf16          -> reused as Yb after vtrans
  //   [24,32)  Vt bf16
  //   [32,40)  PA packed x                -> reused as PY after gemm_qkv
  //   [40,46)  PWq | PWk | PWv (2MB each)
  //   [46,46.25) rope tab
  char* ws = (char*)d_ws;
  u16*   Qb  = (u16*)(ws);
  u16*   Kb  = (u16*)(ws + ((size_t)8 << 20));
  u16*   Vb  = (u16*)(ws + ((size_t)16 << 20));
  u16*   Yb  = Vb;
  u16*   Vt  = (u16*)(ws + ((size_t)24 << 20));
  uint4* PA  = (uint4*)(ws + ((size_t)32 << 20));
  uint4* PY  = PA;
  uint4* PWq = (uint4*)(ws + ((size_t)40 << 20));
  uint4* PWk = (uint4*)(ws + ((size_t)42 << 20));
  uint4* PWv = (uint4*)(ws + ((size_t)44 << 20));
  uint4* PWo = (uint4*)Qb;
  u32*   tab = (u32*)(ws + ((size_t)46 << 20));

  dim3 blk(256);

  pack_w<<<dim3(64, 3), blk, 0, stream>>>(Wq, Wk, Wv, PWq, PWk, PWv);
  pack_a<true><<<dim3(NM / 16), blk, 0, stream>>>(x, PA);
  gemm_qkv<<<dim3(8, 32, 3), blk, 0, stream>>>(PA, PWq, PWk, PWv, Qb, Kb, Vb);
  rope_tab<<<dim3(NL * 32 / 256), blk, 0, stream>>>(tab);
  rope_apply<<<dim3(2 * NM * (ND / 8) / 256), blk, 0, stream>>>(
      (u32*)Qb, (u32*)Kb, tab);
  vtrans<<<dim3(NL / 64, NB * NH), blk, 0, stream>>>(Vb, Vt);
  attn_mfma2<<<dim3(8, NB * NH), blk, 0, stream>>>(Qb, Kb, Vt, Yb);
  pack_a<false><<<dim3(NM / 16), blk, 0, stream>>>(Yb, PY);
  pack_w<<<dim3(64, 1), blk, 0, stream>>>(Wo, Wo, Wo, PWo, PWo, PWo);
  gemm_out<<<dim3(8, 32), blk, 0, stream>>>(PY, PWo, out);
}

// Round 5
// 157.086 us; speedup vs baseline: 37.6238x; 1.0009x over previous
//
#include <hip/hip_runtime.h>
#include <hip/hip_bf16.h>
#include <math.h>

#define NB 2
#define NL 2048
#define ND 1024
#define NH 16
#define NDH 64
#define NM (NB * NL)   // 4096 rows

typedef __bf16 bf16x8 __attribute__((ext_vector_type(8)));
typedef float  f32x4  __attribute__((ext_vector_type(4)));
typedef unsigned int   u32;
typedef unsigned short u16;

union FragU { u32 u[4]; bf16x8 v; };

__device__ __forceinline__ u32 f2bf(float f) {   // RTNE f32 -> bf16 bits
  u32 u = __float_as_uint(f);
  return (u + 0x7fffu + ((u >> 16) & 1u)) >> 16;
}
__device__ __forceinline__ float bf2f(u32 b) { return __uint_as_float(b << 16); }

// async global->LDS, 16B per lane; LDS dest wave-uniform base + lane*16
__device__ __forceinline__ void gload16(const void* g, void* l) {
  __builtin_amdgcn_global_load_lds(
      (const __attribute__((address_space(1))) u32*)g,
      (__attribute__((address_space(3))) u32*)l, 16, 0, 0);
}

// ===========================================================================
// Packed operand layout:
//   P[rb][kc][lane] : 16B chunk, rb = 16-row block, kc = 32-col(k) chunk
//   chunk(rb,kc,l) = { src[16rb+(l&15)][32kc+4(l>>4)+0..3],
//                      src[16rb+(l&15)][32kc+16+4(l>>4)+0..3] }  (bf16)
// One lane's A-frag (rows) / B-frag (cols) for mfma_f32_16x16x32_bf16.
// ===========================================================================

// shared emit phase: Ls[16][1032] bf16 -> 32 kc * 64 lane chunks
__device__ __forceinline__ void pack_emit(const u16 Ls[16][1032],
                                          uint4* __restrict__ dst, int t) {
#pragma unroll
  for (int rep = 0; rep < 8; ++rep) {
    int c  = rep * 256 + t;          // 0..2047
    int kc = c >> 6, l = c & 63;
    int lo = l & 15, hi = l >> 4;
    int k0 = kc * 32 + hi * 4;
    uint4 o;
    o.x = (u32)Ls[lo][k0 + 0]  | ((u32)Ls[lo][k0 + 1]  << 16);
    o.y = (u32)Ls[lo][k0 + 2]  | ((u32)Ls[lo][k0 + 3]  << 16);
    o.z = (u32)Ls[lo][k0 + 16] | ((u32)Ls[lo][k0 + 17] << 16);
    o.w = (u32)Ls[lo][k0 + 18] | ((u32)Ls[lo][k0 + 19] << 16);
    dst[(size_t)kc * 64 + l] = o;
  }
}

// pack a row-major [NM x ND] matrix (fp32 or bf16 input), one block per rb
template <bool F32IN>
__global__ __launch_bounds__(256) void pack_a(const void* __restrict__ src,
                                              uint4* __restrict__ dst) {
  __shared__ u16 Ls[16][1032];
  const int rb = blockIdx.x;
  const int t  = threadIdx.x;
  const int row = t >> 4;
  if (F32IN) {
    const float* S = (const float*)src + (size_t)(rb * 16 + row) * ND;
#pragma unroll
    for (int rep = 0; rep < 16; ++rep) {
      int c0 = (t & 15) * 4 + rep * 64;
      float4 v = *(const float4*)(S + c0);
      Ls[row][c0 + 0] = (u16)f2bf(v.x); Ls[row][c0 + 1] = (u16)f2bf(v.y);
      Ls[row][c0 + 2] = (u16)f2bf(v.z); Ls[row][c0 + 3] = (u16)f2bf(v.w);
    }
  } else {
    const u16* S = (const u16*)src + (size_t)(rb * 16 + row) * ND;
#pragma unroll
    for (int rep = 0; rep < 8; ++rep) {
      int c0 = (t & 15) * 8 + rep * 128;
      uint4 v = *(const uint4*)(S + c0);
      u32 a[4] = {v.x, v.y, v.z, v.w};
#pragma unroll
      for (int jj = 0; jj < 4; ++jj) {
        Ls[row][c0 + 2 * jj]     = (u16)(a[jj] & 0xffffu);
        Ls[row][c0 + 2 * jj + 1] = (u16)(a[jj] >> 16);
      }
    }
  }
  __syncthreads();
  pack_emit(Ls, dst + (size_t)rb * 32 * 64, t);
}

// pack W (k x n row-major fp32) as W^T fragments: one block per 16-col slice
__global__ __launch_bounds__(256) void pack_w(const float* __restrict__ W0,
                                              const float* __restrict__ W1,
                                              const float* __restrict__ W2,
                                              uint4* __restrict__ P0,
                                              uint4* __restrict__ P1,
                                              uint4* __restrict__ P2) {
  const float* W = (blockIdx.y == 0) ? W0 : (blockIdx.y == 1) ? W1 : W2;
  uint4* P       = (blockIdx.y == 0) ? P0 : (blockIdx.y == 1) ? P1 : P2;
  __shared__ u16 Ls[16][1032];
  const int n16 = blockIdx.x;
  const int t   = threadIdx.x;
  const int n0  = n16 * 16;
#pragma unroll
  for (int rep = 0; rep < 16; ++rep) {
    int k  = rep * 64 + (t >> 2);
    int c4 = (t & 3) * 4;
    float4 v = *(const float4*)(W + (size_t)k * ND + n0 + c4);
    Ls[c4 + 0][k] = (u16)f2bf(v.x); Ls[c4 + 1][k] = (u16)f2bf(v.y);
    Ls[c4 + 2][k] = (u16)f2bf(v.z); Ls[c4 + 3][k] = (u16)f2bf(v.w);
  }
  __syncthreads();
  pack_emit(Ls, P + (size_t)n16 * 32 * 64, t);
}

// ===========================================================================
// bf16 MFMA GEMM, m97 structure: 128x128 tile, BK=32, 4 waves (2x2),
// global_load_lds staging, ds_read_b128 fragment reads, 16 MFMA / K-step.
// ===========================================================================
template <bool F32OUT>
__device__ __forceinline__ void gemm_mfma_body(const uint4* __restrict__ PA,
                                               const uint4* __restrict__ PB,
                                               void* __restrict__ Cv,
                                               float scale, int bx, int by) {
  __shared__ uint4 As[512];   // 8KB: [m-local 0..7][lane]
  __shared__ uint4 Bs[512];
  const int t  = threadIdx.x;
  const int w  = t >> 6, l = t & 63;
  const int lo = l & 15, hi = l >> 4;
  const int wr = w >> 1, wc = w & 1;

  const uint4* pa0 = PA + ((size_t)(by * 8 + w * 2 + 0) * 32) * 64 + l;
  const uint4* pa1 = PA + ((size_t)(by * 8 + w * 2 + 1) * 32) * 64 + l;
  const uint4* pb0 = PB + ((size_t)(bx * 8 + w * 2 + 0) * 32) * 64 + l;
  const uint4* pb1 = PB + ((size_t)(bx * 8 + w * 2 + 1) * 32) * 64 + l;
  uint4* as0 = &As[(w * 2 + 0) * 64];
  uint4* as1 = &As[(w * 2 + 1) * 64];
  uint4* bs0 = &Bs[(w * 2 + 0) * 64];
  uint4* bs1 = &Bs[(w * 2 + 1) * 64];

  f32x4 acc[4][4];
#pragma unroll
  for (int i = 0; i < 4; ++i)
#pragma unroll
    for (int j = 0; j < 4; ++j) acc[i][j] = (f32x4){0.f, 0.f, 0.f, 0.f};

  for (int kc = 0; kc < 32; ++kc) {
    __syncthreads();                         // prior tile's reads complete
    gload16(pa0 + kc * 64, as0);
    gload16(pa1 + kc * 64, as1);
    gload16(pb0 + kc * 64, bs0);
    gload16(pb1 + kc * 64, bs1);
    __syncthreads();                         // staging complete (vmcnt drained)

    FragU a[4], b[4];
#pragma unroll
    for (int i = 0; i < 4; ++i) *(uint4*)a[i].u = As[(wr * 4 + i) * 64 + l];
#pragma unroll
    for (int j = 0; j < 4; ++j) *(uint4*)b[j].u = Bs[(wc * 4 + j) * 64 + l];
#pragma unroll
    for (int i = 0; i < 4; ++i)
#pragma unroll
      for (int j = 0; j < 4; ++j)
        acc[i][j] = __builtin_amdgcn_mfma_f32_16x16x32_bf16(a[i].v, b[j].v,
                                                            acc[i][j], 0, 0, 0);
  }

  // D layout: row = hi*4 + reg, col = lo (within each 16x16 fragment)
  const int row0 = by * 128 + wr * 64 + hi * 4;
  const int col0 = bx * 128 + wc * 64 + lo;
#pragma unroll
  for (int i = 0; i < 4; ++i)
#pragma unroll
    for (int reg = 0; reg < 4; ++reg) {
      const size_t rbase = (size_t)(row0 + i * 16 + reg) * ND + col0;
      if (F32OUT) {
        float* C = (float*)Cv;
#pragma unroll
        for (int j = 0; j < 4; ++j) C[rbase + j * 16] = acc[i][j][reg] * scale;
      } else {
        u16* C = (u16*)Cv;
#pragma unroll
        for (int j = 0; j < 4; ++j)
          C[rbase + j * 16] = (u16)f2bf(acc[i][j][reg] * scale);
      }
    }
}

__global__ __launch_bounds__(256) void gemm_qkv(const uint4* __restrict__ PA,
                                                const uint4* __restrict__ PWq,
                                                const uint4* __restrict__ PWk,
                                                const uint4* __restrict__ PWv,
                                                u16* __restrict__ Qb,
                                                u16* __restrict__ Kb,
                                                u16* __restrict__ Vb) {
  const uint4* PB;
  u16* C;
  float scale;
  // q scale = 1/sqrt(1024) * log2(e)  (softmax runs in base-2 domain)
  if (blockIdx.z == 0)      { PB = PWq; C = Qb; scale = 0.03125f * 1.44269504f; }
  else if (blockIdx.z == 1) { PB = PWk; C = Kb; scale = 1.f; }
  else                      { PB = PWv; C = Vb; scale = 1.f; }
  gemm_mfma_body<false>(PA, PB, C, scale, blockIdx.x, blockIdx.y);
}

__global__ __launch_bounds__(256) void gemm_out(const uint4* __restrict__ PY,
                                                const uint4* __restrict__ PWo,
                                                float* __restrict__ C) {
  gemm_mfma_body<true>(PY, PWo, C, 1.f, blockIdx.x, blockIdx.y);
}

// ---------------------------------------------------------------------------
// RoPE cos/sin table: tab[l*32+p] = bf16(cos)|bf16(sin)<<16
// ---------------------------------------------------------------------------
__global__ __launch_bounds__(256) void rope_tab(u32* __restrict__ tab) {
  int i = blockIdx.x * 256 + threadIdx.x;      // 0..65535
  int l = i >> 5, p = i & 31;
  float invf = expf(-(float)p * 0.28782313662425572f);   // ln(10000)/32
  float ang = (float)l * invf;
  float sn, cs;
  sincosf(ang, &sn, &cs);
  tab[i] = f2bf(cs) | (f2bf(sn) << 16);
}

// RoPE applied in place to bf16 Q and K (row-major). One thread = 8 bf16.
__global__ __launch_bounds__(256) void rope_apply(u32* __restrict__ Qb,
                                                  u32* __restrict__ Kb,
                                                  const u32* __restrict__ tab) {
  const int PER = NM * (ND / 8);
  int i = blockIdx.x * 256 + threadIdx.x;
  uint4* base = (uint4*)Qb;
  if (i >= PER) { base = (uint4*)Kb; i -= PER; }
  int row = i >> 7;
  int ch  = i & 127;
  int l   = row & (NL - 1);
  int p0  = (ch & 7) * 4;
  uint4 v = base[i];
  const u32* tp = tab + l * 32 + p0;
  u32 vv[4] = {v.x, v.y, v.z, v.w};
  u32 oo[4];
#pragma unroll
  for (int j = 0; j < 4; ++j) {
    u32 cs = tp[j];
    float c = bf2f(cs & 0xffffu), s = bf2f(cs >> 16);
    float x0 = bf2f(vv[j] & 0xffffu), x1 = bf2f(vv[j] >> 16);
    oo[j] = f2bf(x0 * c - x1 * s) | (f2bf(x1 * c + x0 * s) << 16);
  }
  base[i] = make_uint4(oo[0], oo[1], oo[2], oo[3]);
}

// ---------------------------------------------------------------------------
// V transpose: Vb[b,l,h,d] bf16 -> Vt[(b,h), d, l] bf16
// ---------------------------------------------------------------------------
__global__ __launch_bounds__(256) void vtrans(const u16* __restrict__ Vb,
                                              u16* __restrict__ Vt) {
  __shared__ u16 Ls[64][80];
  const int bh = blockIdx.y;
  const int lt = blockIdx.x;
  const int b = bh >> 4, h = bh & 15;
  const int t = threadIdx.x;
  const int l0 = lt * 64;
#pragma unroll
  for (int rep = 0; rep < 2; ++rep) {
    int idx = rep * 256 + t;
    int lrow = idx >> 3, c8 = idx & 7;
    uint4 v = *(const uint4*)(Vb + (size_t)(b * NL + l0 + lrow) * ND + h * 64 + c8 * 8);
    *(uint4*)&Ls[lrow][c8 * 8] = v;
  }
  __syncthreads();
#pragma unroll
  for (int rep = 0; rep < 2; ++rep) {
    int idx = rep * 256 + t;
    int d = idx >> 3, lq = idx & 7;
    u32 wds[4];
#pragma unroll
    for (int jj = 0; jj < 4; ++jj)
      wds[jj] = (u32)Ls[lq * 8 + 2 * jj][d] | ((u32)Ls[lq * 8 + 2 * jj + 1][d] << 16);
    *(uint4*)(Vt + (size_t)(bh * 64 + d) * NL + l0 + lq * 8) =
        make_uint4(wds[0], wds[1], wds[2], wds[3]);
  }
}

// ---------------------------------------------------------------------------
// Causal flash attention v3: QBLK=64 (4 waves x 16 rows), fold-balanced:
// block (fi,bh) does q-tiles fi and 31-fi -> 33 KV-iters each; grid 512
// -> 2 blocks/CU -> 2 waves/SIMD (TLP hides the softmax/MFMA dep chains).
// Double-buffered LDS + register prefetch, one barrier/iter.
// Defer-max (THR=8, base-2): skip y-rescale unless max grew (T13).
// s_setprio(1) around MFMA clusters (T5). P-pack via casts (cvt_pk).
// ---------------------------------------------------------------------------
__global__ __launch_bounds__(256, 2) void attn_mfma3(
    const u16* __restrict__ Qb,
    const u16* __restrict__ Kb,
    const u16* __restrict__ Vt,
    u16* __restrict__ Y) {
  __shared__ uint4 Ks2[2][512];   // 16KB: [buf][ (kg*2+c32)*64 + lane ]
  __shared__ uint4 Vs2[2][512];   // 16KB: [buf][ (et*2+c32)*64 + lane ]

  const int fi = blockIdx.x;           // 0..15
  const int bh = blockIdx.y;           // 0..31
  const int b = bh >> 4, h = bh & 15;
  const int t = threadIdx.x;
  const int w = t >> 6, l = t & 63;
  const int lo = l & 15, hi = l >> 4;
  const int hi4 = hi * 4;
  const int rloc = w * 16 + lo;        // lane's q-row within the 64-row tile

  // ---- staging decode (per thread: 2 K chunks + 2 V chunks per tile)
  const char* kbase = (const char*)(Kb + (size_t)b * NL * ND + h * 64);
  const char* vbase = (const char*)(Vt + (size_t)bh * 64 * NL);
  const char* pK[2];
  const char* pV[2];
  int cid[2];
#pragma unroll
  for (int r = 0; r < 2; ++r) {
    int c = r * 256 + t;                 // 0..511
    cid[r] = c;
    int lc = c & 63;
    int pair = c >> 6;                   // 0..7
    int g16 = pair >> 1;
    int c32 = pair & 1;
    int row = g16 * 16 + (lc & 15);
    int offA = c32 * 64 + ((lc >> 4) << 3);
    pK[r] = kbase + (size_t)row * (ND * 2) + offA;
    pV[r] = vbase + (size_t)row * (NL * 2) + offA;
  }
  const size_t KTS = (size_t)64 * ND * 2;   // K tile byte stride
  const size_t VTS = 128;                   // V tile byte stride

  // ---- prologue: stage tile 0 into buffer 0
#pragma unroll
  for (int r = 0; r < 2; ++r) {
    uint2 a = *(const uint2*)pK[r];
    uint2 b2 = *(const uint2*)(pK[r] + 32);
    Ks2[0][cid[r]] = make_uint4(a.x, a.y, b2.x, b2.y);
    uint2 c = *(const uint2*)pV[r];
    uint2 d2 = *(const uint2*)(pV[r] + 32);
    Vs2[0][cid[r]] = make_uint4(c.x, c.y, d2.x, d2.y);
  }
  int cur = 0;

  for (int ph = 0; ph < 2; ++ph) {
    const int qt = ph ? (31 - fi) : fi;
    const int nkt = qt + 1;

    // ---- Q B-fragments (row = qt*64 + rloc)
    FragU qf[2];
    {
      const char* qc = (const char*)(Qb +
          ((size_t)(b * NL + qt * 64 + rloc)) * ND + h * 64);
      uint2 a0 = *(const uint2*)(qc + hi * 8);
      uint2 b0 = *(const uint2*)(qc + hi * 8 + 32);
      uint2 a1 = *(const uint2*)(qc + hi * 8 + 64);
      uint2 b1 = *(const uint2*)(qc + hi * 8 + 96);
      qf[0].u[0] = a0.x; qf[0].u[1] = a0.y; qf[0].u[2] = b0.x; qf[0].u[3] = b0.y;
      qf[1].u[0] = a1.x; qf[1].u[1] = a1.y; qf[1].u[2] = b1.x; qf[1].u[3] = b1.y;
    }

    float m_run = -1e30f, l_run = 0.f;
    f32x4 y[4];
#pragma unroll
    for (int et = 0; et < 4; ++et) y[et] = (f32x4){0.f, 0.f, 0.f, 0.f};

    for (int kt = 0; kt < nkt; ++kt) {
      __syncthreads();   // LDS[cur] staged & prior reads of LDS[cur^1] done

      // ---- prefetch next tile into registers (seam -> tile 0 of phase B)
      int ktn = (kt + 1 < nkt) ? kt + 1 : (ph == 0 ? 0 : kt);
      uint4 nk[2], nv[2];
#pragma unroll
      for (int r = 0; r < 2; ++r) {
        const char* sk = pK[r] + (size_t)ktn * KTS;
        uint2 a = *(const uint2*)sk;
        uint2 b2 = *(const uint2*)(sk + 32);
        nk[r] = make_uint4(a.x, a.y, b2.x, b2.y);
        const char* sv = pV[r] + (size_t)ktn * VTS;
        uint2 c = *(const uint2*)sv;
        uint2 d2 = *(const uint2*)(sv + 32);
        nv[r] = make_uint4(c.x, c.y, d2.x, d2.y);
      }

      // ---- S^T = K * Q^T : s[kg][reg] = S[row=rloc][key = kg*16+hi4+reg]
      f32x4 s[4];
      __builtin_amdgcn_s_setprio(1);
#pragma unroll
      for (int kg = 0; kg < 4; ++kg) {
        s[kg] = (f32x4){0.f, 0.f, 0.f, 0.f};
#pragma unroll
        for (int c32 = 0; c32 < 2; ++c32) {
          FragU kf;
          *(uint4*)kf.u = Ks2[cur][(kg * 2 + c32) * 64 + l];
          s[kg] = __builtin_amdgcn_mfma_f32_16x16x32_bf16(kf.v, qf[c32].v,
                                                          s[kg], 0, 0, 0);
        }
      }
      __builtin_amdgcn_s_setprio(0);

      // ---- causal mask (diagonal tile only)
      if (kt == qt) {
#pragma unroll
        for (int kg = 0; kg < 4; ++kg)
#pragma unroll
          for (int reg = 0; reg < 4; ++reg)
            if (kg * 16 + hi4 + reg > rloc) s[kg][reg] = -1e30f;
      }

      // ---- online softmax (base 2), defer-max (row vals in lanes lo+16k)
      float mt = s[0][0];
#pragma unroll
      for (int kg = 0; kg < 4; ++kg)
#pragma unroll
        for (int reg = 0; reg < 4; ++reg) mt = fmaxf(mt, s[kg][reg]);
      mt = fmaxf(mt, __shfl_xor(mt, 16));
      mt = fmaxf(mt, __shfl_xor(mt, 32));
      if (__any(mt > m_run + 8.f)) {       // wave-uniform branch
        const float mnew = fmaxf(m_run, mt);
        const float corr = exp2f(m_run - mnew);
        m_run = mnew;
        l_run *= corr;
        const float c0 = __shfl(corr, hi4 + 0);
        const float c1 = __shfl(corr, hi4 + 1);
        const float c2 = __shfl(corr, hi4 + 2);
        const float c3 = __shfl(corr, hi4 + 3);
#pragma unroll
        for (int et = 0; et < 4; ++et) {
          y[et][0] *= c0; y[et][1] *= c1; y[et][2] *= c2; y[et][3] *= c3;
        }
      }
      float ps = 0.f;
#pragma unroll
      for (int kg = 0; kg < 4; ++kg)
#pragma unroll
        for (int reg = 0; reg < 4; ++reg) {
          float e = exp2f(s[kg][reg] - m_run);
          s[kg][reg] = e;
          ps += e;
        }
      ps += __shfl_xor(ps, 16);
      ps += __shfl_xor(ps, 32);
      l_run += ps;

      // ---- P A-fragments via casts (compiler emits v_cvt_pk_bf16_f32)
      FragU pa0, pa1;
#pragma unroll
      for (int kg = 0; kg < 2; ++kg)
#pragma unroll
        for (int reg = 0; reg < 4; ++reg) {
          pa0.v[kg * 4 + reg] = (__bf16)s[kg][reg];
          pa1.v[kg * 4 + reg] = (__bf16)s[kg + 2][reg];
        }

      // ---- PV: y[et] += P * V
      __builtin_amdgcn_s_setprio(1);
#pragma unroll
      for (int et = 0; et < 4; ++et) {
        FragU vf0, vf1;
        *(uint4*)vf0.u = Vs2[cur][(et * 2 + 0) * 64 + l];
        *(uint4*)vf1.u = Vs2[cur][(et * 2 + 1) * 64 + l];
        y[et] = __builtin_amdgcn_mfma_f32_16x16x32_bf16(pa0.v, vf0.v, y[et], 0, 0, 0);
        y[et] = __builtin_amdgcn_mfma_f32_16x16x32_bf16(pa1.v, vf1.v, y[et], 0, 0, 0);
      }
      __builtin_amdgcn_s_setprio(0);

      // ---- write prefetched tile to the other buffer
#pragma unroll
      for (int r = 0; r < 2; ++r) {
        Ks2[cur ^ 1][cid[r]] = nk[r];
        Vs2[cur ^ 1][cid[r]] = nv[r];
      }
      cur ^= 1;
    }

    // ---- phase epilogue: normalize and store (rows hi4+reg, col et*16+lo)
    {
      const float li0 = 1.f / __shfl(l_run, hi4 + 0);
      const float li1 = 1.f / __shfl(l_run, hi4 + 1);
      const float li2 = 1.f / __shfl(l_run, hi4 + 2);
      const float li3 = 1.f / __shfl(l_run, hi4 + 3);
      __bf16* Yb16 = (__bf16*)Y;
      const size_t ybase = (size_t)(b * NL + qt * 64 + w * 16) * ND + h * 64;
#pragma unroll
      for (int et = 0; et < 4; ++et) {
        Yb16[ybase + (size_t)(hi4 + 0) * ND + et * 16 + lo] = (__bf16)(y[et][0] * li0);
        Yb16[ybase + (size_t)(hi4 + 1) * ND + et * 16 + lo] = (__bf16)(y[et][1] * li1);
        Yb16[ybase + (size_t)(hi4 + 2) * ND + et * 16 + lo] = (__bf16)(y[et][2] * li2);
        Yb16[ybase + (size_t)(hi4 + 3) * ND + et * 16 + lo] = (__bf16)(y[et][3] * li3);
      }
    }
  }
}

// ---------------------------------------------------------------------------
extern "C" void kernel_launch(void* const* d_in, const int* in_sizes, int n_in,
                              void* d_out, int out_size, void* d_ws,
                              size_t ws_size, hipStream_t stream) {
  const float* x  = (const float*)d_in[0];
  const float* Wq = (const float*)d_in[1];
  const float* Wk = (const float*)d_in[2];
  const float* Wv = (const float*)d_in[3];
  const float* Wo = (const float*)d_in[4];
  float* out = (float*)d_out;

  // workspace layout (46.25 MB):
  //   [0,8)    Qb row-major bf16          -> reused for PWo after attn
  //   [8,16)   Kb row-major bf16
  //   [16,24)  Vb row-major bf16          -> reused as Yb after vtrans
  //   [24,32)  Vt bf16
  //   [32,40)  PA packed x                -> reused as PY after gemm_qkv
  //   [40,46)  PWq | PWk | PWv (2MB each)
  //   [46,46.25) rope tab
  char* ws = (char*)d_ws;
  u16*   Qb  = (u16*)(ws);
  u16*   Kb  = (u16*)(ws + ((size_t)8 << 20));
  u16*   Vb  = (u16*)(ws + ((size_t)16 << 20));
  u16*   Yb  = Vb;
  u16*   Vt  = (u16*)(ws + ((size_t)24 << 20));
  uint4* PA  = (uint4*)(ws + ((size_t)32 << 20));
  uint4* PY  = PA;
  uint4* PWq = (uint4*)(ws + ((size_t)40 << 20));
  uint4* PWk = (uint4*)(ws + ((size_t)42 << 20));
  uint4* PWv = (uint4*)(ws + ((size_t)44 << 20));
  uint4* PWo = (uint4*)Qb;
  u32*   tab = (u32*)(ws + ((size_t)46 << 20));

  dim3 blk(256);

  pack_w<<<dim3(64, 3), blk, 0, stream>>>(Wq, Wk, Wv, PWq, PWk, PWv);
  pack_a<true><<<dim3(NM / 16), blk, 0, stream>>>(x, PA);
  gemm_qkv<<<dim3(8, 32, 3), blk, 0, stream>>>(PA, PWq, PWk, PWv, Qb, Kb, Vb);
  rope_tab<<<dim3(NL * 32 / 256), blk, 0, stream>>>(tab);
  rope_apply<<<dim3(2 * NM * (ND / 8) / 256), blk, 0, stream>>>(
      (u32*)Qb, (u32*)Kb, tab);
  vtrans<<<dim3(NL / 64, NB * NH), blk, 0, stream>>>(Vb, Vt);
  attn_mfma3<<<dim3(16, NB * NH), blk, 0, stream>>>(Qb, Kb, Vt, Yb);
  pack_a<false><<<dim3(NM / 16), blk, 0, stream>>>(Yb, PY);
  pack_w<<<dim3(64, 1), blk, 0, stream>>>(Wo, Wo, Wo, PWo, PWo, PWo);
  gemm_out<<<dim3(8, 32), blk, 0, stream>>>(PY, PWo, out);
}

// Round 6
// 139.687 us; speedup vs baseline: 42.3102x; 1.1246x over previous
//
#include <hip/hip_runtime.h>
#include <hip/hip_bf16.h>
#include <math.h>

#define NB 2
#define NL 2048
#define ND 1024
#define NH 16
#define NDH 64
#define NM (NB * NL)   // 4096 rows

typedef __bf16 bf16x8 __attribute__((ext_vector_type(8)));
typedef float  f32x4  __attribute__((ext_vector_type(4)));
typedef unsigned int   u32;
typedef unsigned short u16;

union FragU { u32 u[4]; bf16x8 v; };

__device__ __forceinline__ u32 f2bf(float f) {   // RTNE f32 -> bf16 bits
  u32 u = __float_as_uint(f);
  return (u + 0x7fffu + ((u >> 16) & 1u)) >> 16;
}
__device__ __forceinline__ float bf2f(u32 b) { return __uint_as_float(b << 16); }

// async global->LDS, 16B per lane; LDS dest wave-uniform base + lane*16
__device__ __forceinline__ void gload16(const void* g, void* l) {
  __builtin_amdgcn_global_load_lds(
      (const __attribute__((address_space(1))) u32*)g,
      (__attribute__((address_space(3))) u32*)l, 16, 0, 0);
}

// ===========================================================================
// Packed operand layout:
//   P[rb][kc][lane] : 16B chunk, rb = 16-row block, kc = 32-col(k) chunk
//   chunk(rb,kc,l) = { src[16rb+(l&15)][32kc+4(l>>4)+0..3],
//                      src[16rb+(l&15)][32kc+16+4(l>>4)+0..3] }  (bf16)
// One lane's A-frag (rows) / B-frag (cols) for mfma_f32_16x16x32_bf16.
// ===========================================================================

// shared emit phase: Ls[16][1032] bf16 -> 32 kc * 64 lane chunks
__device__ __forceinline__ void pack_emit(const u16 Ls[16][1032],
                                          uint4* __restrict__ dst, int t) {
#pragma unroll
  for (int rep = 0; rep < 8; ++rep) {
    int c  = rep * 256 + t;          // 0..2047
    int kc = c >> 6, l = c & 63;
    int lo = l & 15, hi = l >> 4;
    int k0 = kc * 32 + hi * 4;
    uint4 o;
    o.x = (u32)Ls[lo][k0 + 0]  | ((u32)Ls[lo][k0 + 1]  << 16);
    o.y = (u32)Ls[lo][k0 + 2]  | ((u32)Ls[lo][k0 + 3]  << 16);
    o.z = (u32)Ls[lo][k0 + 16] | ((u32)Ls[lo][k0 + 17] << 16);
    o.w = (u32)Ls[lo][k0 + 18] | ((u32)Ls[lo][k0 + 19] << 16);
    dst[(size_t)kc * 64 + l] = o;
  }
}

// pack a row-major [NM x ND] matrix (fp32 or bf16 input), one block per rb
template <bool F32IN>
__global__ __launch_bounds__(256) void pack_a(const void* __restrict__ src,
                                              uint4* __restrict__ dst) {
  __shared__ u16 Ls[16][1032];
  const int rb = blockIdx.x;
  const int t  = threadIdx.x;
  const int row = t >> 4;
  if (F32IN) {
    const float* S = (const float*)src + (size_t)(rb * 16 + row) * ND;
#pragma unroll
    for (int rep = 0; rep < 16; ++rep) {
      int c0 = (t & 15) * 4 + rep * 64;
      float4 v = *(const float4*)(S + c0);
      Ls[row][c0 + 0] = (u16)f2bf(v.x); Ls[row][c0 + 1] = (u16)f2bf(v.y);
      Ls[row][c0 + 2] = (u16)f2bf(v.z); Ls[row][c0 + 3] = (u16)f2bf(v.w);
    }
  } else {
    const u16* S = (const u16*)src + (size_t)(rb * 16 + row) * ND;
#pragma unroll
    for (int rep = 0; rep < 8; ++rep) {
      int c0 = (t & 15) * 8 + rep * 128;
      uint4 v = *(const uint4*)(S + c0);
      u32 a[4] = {v.x, v.y, v.z, v.w};
#pragma unroll
      for (int jj = 0; jj < 4; ++jj) {
        Ls[row][c0 + 2 * jj]     = (u16)(a[jj] & 0xffffu);
        Ls[row][c0 + 2 * jj + 1] = (u16)(a[jj] >> 16);
      }
    }
  }
  __syncthreads();
  pack_emit(Ls, dst + (size_t)rb * 32 * 64, t);
}

// pack W (k x n row-major fp32) as W^T fragments: one block per 16-col slice
__global__ __launch_bounds__(256) void pack_w(const float* __restrict__ W0,
                                              const float* __restrict__ W1,
                                              const float* __restrict__ W2,
                                              uint4* __restrict__ P0,
                                              uint4* __restrict__ P1,
                                              uint4* __restrict__ P2) {
  const float* W = (blockIdx.y == 0) ? W0 : (blockIdx.y == 1) ? W1 : W2;
  uint4* P       = (blockIdx.y == 0) ? P0 : (blockIdx.y == 1) ? P1 : P2;
  __shared__ u16 Ls[16][1032];
  const int n16 = blockIdx.x;
  const int t   = threadIdx.x;
  const int n0  = n16 * 16;
#pragma unroll
  for (int rep = 0; rep < 16; ++rep) {
    int k  = rep * 64 + (t >> 2);
    int c4 = (t & 3) * 4;
    float4 v = *(const float4*)(W + (size_t)k * ND + n0 + c4);
    Ls[c4 + 0][k] = (u16)f2bf(v.x); Ls[c4 + 1][k] = (u16)f2bf(v.y);
    Ls[c4 + 2][k] = (u16)f2bf(v.z); Ls[c4 + 3][k] = (u16)f2bf(v.w);
  }
  __syncthreads();
  pack_emit(Ls, P + (size_t)n16 * 32 * 64, t);
}

// ===========================================================================
// bf16 MFMA GEMM, m97 structure: 128x128 tile, BK=32, 4 waves (2x2),
// global_load_lds staging, ds_read_b128 fragment reads, 16 MFMA / K-step.
// ===========================================================================
template <bool F32OUT>
__device__ __forceinline__ void gemm_mfma_body(const uint4* __restrict__ PA,
                                               const uint4* __restrict__ PB,
                                               void* __restrict__ Cv,
                                               float scale, int bx, int by) {
  __shared__ uint4 As[512];   // 8KB: [m-local 0..7][lane]
  __shared__ uint4 Bs[512];
  const int t  = threadIdx.x;
  const int w  = t >> 6, l = t & 63;
  const int lo = l & 15, hi = l >> 4;
  const int wr = w >> 1, wc = w & 1;

  const uint4* pa0 = PA + ((size_t)(by * 8 + w * 2 + 0) * 32) * 64 + l;
  const uint4* pa1 = PA + ((size_t)(by * 8 + w * 2 + 1) * 32) * 64 + l;
  const uint4* pb0 = PB + ((size_t)(bx * 8 + w * 2 + 0) * 32) * 64 + l;
  const uint4* pb1 = PB + ((size_t)(bx * 8 + w * 2 + 1) * 32) * 64 + l;
  uint4* as0 = &As[(w * 2 + 0) * 64];
  uint4* as1 = &As[(w * 2 + 1) * 64];
  uint4* bs0 = &Bs[(w * 2 + 0) * 64];
  uint4* bs1 = &Bs[(w * 2 + 1) * 64];

  f32x4 acc[4][4];
#pragma unroll
  for (int i = 0; i < 4; ++i)
#pragma unroll
    for (int j = 0; j < 4; ++j) acc[i][j] = (f32x4){0.f, 0.f, 0.f, 0.f};

  for (int kc = 0; kc < 32; ++kc) {
    __syncthreads();                         // prior tile's reads complete
    gload16(pa0 + kc * 64, as0);
    gload16(pa1 + kc * 64, as1);
    gload16(pb0 + kc * 64, bs0);
    gload16(pb1 + kc * 64, bs1);
    __syncthreads();                         // staging complete (vmcnt drained)

    FragU a[4], b[4];
#pragma unroll
    for (int i = 0; i < 4; ++i) *(uint4*)a[i].u = As[(wr * 4 + i) * 64 + l];
#pragma unroll
    for (int j = 0; j < 4; ++j) *(uint4*)b[j].u = Bs[(wc * 4 + j) * 64 + l];
#pragma unroll
    for (int i = 0; i < 4; ++i)
#pragma unroll
      for (int j = 0; j < 4; ++j)
        acc[i][j] = __builtin_amdgcn_mfma_f32_16x16x32_bf16(a[i].v, b[j].v,
                                                            acc[i][j], 0, 0, 0);
  }

  // D layout: row = hi*4 + reg, col = lo (within each 16x16 fragment)
  const int row0 = by * 128 + wr * 64 + hi * 4;
  const int col0 = bx * 128 + wc * 64 + lo;
#pragma unroll
  for (int i = 0; i < 4; ++i)
#pragma unroll
    for (int reg = 0; reg < 4; ++reg) {
      const size_t rbase = (size_t)(row0 + i * 16 + reg) * ND + col0;
      if (F32OUT) {
        float* C = (float*)Cv;
#pragma unroll
        for (int j = 0; j < 4; ++j) C[rbase + j * 16] = acc[i][j][reg] * scale;
      } else {
        u16* C = (u16*)Cv;
#pragma unroll
        for (int j = 0; j < 4; ++j)
          C[rbase + j * 16] = (u16)f2bf(acc[i][j][reg] * scale);
      }
    }
}

__global__ __launch_bounds__(256) void gemm_qkv(const uint4* __restrict__ PA,
                                                const uint4* __restrict__ PWq,
                                                const uint4* __restrict__ PWk,
                                                const uint4* __restrict__ PWv,
                                                u16* __restrict__ Qb,
                                                u16* __restrict__ Kb,
                                                u16* __restrict__ Vb) {
  const uint4* PB;
  u16* C;
  float scale;
  // q scale = 1/sqrt(1024) * log2(e)  (softmax runs in base-2 domain)
  if (blockIdx.z == 0)      { PB = PWq; C = Qb; scale = 0.03125f * 1.44269504f; }
  else if (blockIdx.z == 1) { PB = PWk; C = Kb; scale = 1.f; }
  else                      { PB = PWv; C = Vb; scale = 1.f; }
  gemm_mfma_body<false>(PA, PB, C, scale, blockIdx.x, blockIdx.y);
}

__global__ __launch_bounds__(256) void gemm_out(const uint4* __restrict__ PY,
                                                const uint4* __restrict__ PWo,
                                                float* __restrict__ C) {
  gemm_mfma_body<true>(PY, PWo, C, 1.f, blockIdx.x, blockIdx.y);
}

// ---------------------------------------------------------------------------
// RoPE cos/sin table: tab[l*32+p] = bf16(cos)|bf16(sin)<<16
// ---------------------------------------------------------------------------
__global__ __launch_bounds__(256) void rope_tab(u32* __restrict__ tab) {
  int i = blockIdx.x * 256 + threadIdx.x;      // 0..65535
  int l = i >> 5, p = i & 31;
  float invf = expf(-(float)p * 0.28782313662425572f);   // ln(10000)/32
  float ang = (float)l * invf;
  float sn, cs;
  sincosf(ang, &sn, &cs);
  tab[i] = f2bf(cs) | (f2bf(sn) << 16);
}

// RoPE applied in place to bf16 Q and K (row-major). One thread = 8 bf16.
__global__ __launch_bounds__(256) void rope_apply(u32* __restrict__ Qb,
                                                  u32* __restrict__ Kb,
                                                  const u32* __restrict__ tab) {
  const int PER = NM * (ND / 8);
  int i = blockIdx.x * 256 + threadIdx.x;
  uint4* base = (uint4*)Qb;
  if (i >= PER) { base = (uint4*)Kb; i -= PER; }
  int row = i >> 7;
  int ch  = i & 127;
  int l   = row & (NL - 1);
  int p0  = (ch & 7) * 4;
  uint4 v = base[i];
  const u32* tp = tab + l * 32 + p0;
  u32 vv[4] = {v.x, v.y, v.z, v.w};
  u32 oo[4];
#pragma unroll
  for (int j = 0; j < 4; ++j) {
    u32 cs = tp[j];
    float c = bf2f(cs & 0xffffu), s = bf2f(cs >> 16);
    float x0 = bf2f(vv[j] & 0xffffu), x1 = bf2f(vv[j] >> 16);
    oo[j] = f2bf(x0 * c - x1 * s) | (f2bf(x1 * c + x0 * s) << 16);
  }
  base[i] = make_uint4(oo[0], oo[1], oo[2], oo[3]);
}

// ---------------------------------------------------------------------------
// pack_vt: Vb[b,l,h,d] bf16 -> PVp fragment chunks of Vt (rows=d, cols=seq).
// Chunk(rb = bh*4+dd, kc = kt*2+c32, lane l):
//   { Vt[16rb'+lo][32kc+4hi+0..3], Vt[16rb'+lo][32kc+16+4hi+0..3] },
// i.e. V[seq = kc*32 (+16) + 4hi + j][d = dd*16+lo]. One pass via LDS bounce.
// ---------------------------------------------------------------------------
__global__ __launch_bounds__(256) void pack_vt(const u16* __restrict__ Vb,
                                               uint4* __restrict__ PVp) {
  __shared__ u16 Ls[64][72];
  const int kt = blockIdx.x;           // seq tile 0..31
  const int bh = blockIdx.y;           // 0..31
  const int b = bh >> 4, h = bh & 15;
  const int t = threadIdx.x;
#pragma unroll
  for (int rep = 0; rep < 2; ++rep) {
    int idx = rep * 256 + t;           // 0..511
    int s = idx >> 3, c8 = idx & 7;
    uint4 v = *(const uint4*)(Vb + ((size_t)(b * NL + kt * 64 + s)) * ND +
                              h * 64 + c8 * 8);
    *(uint4*)&Ls[s][c8 * 8] = v;
  }
  __syncthreads();
#pragma unroll
  for (int rep = 0; rep < 2; ++rep) {
    int idx = rep * 256 + t;           // 0..511
    int dd = idx >> 7;                 // 0..3 (d block = et)
    int rem = idx & 127;
    int c32 = rem >> 6, l2 = rem & 63;
    int lo = l2 & 15, hi = l2 >> 4;
    int sb = c32 * 32 + 4 * hi;
    int d = dd * 16 + lo;
    uint4 o;
    o.x = (u32)Ls[sb + 0][d]  | ((u32)Ls[sb + 1][d]  << 16);
    o.y = (u32)Ls[sb + 2][d]  | ((u32)Ls[sb + 3][d]  << 16);
    o.z = (u32)Ls[sb + 16][d] | ((u32)Ls[sb + 17][d] << 16);
    o.w = (u32)Ls[sb + 18][d] | ((u32)Ls[sb + 19][d] << 16);
    PVp[(((size_t)bh * 4 + dd) * 64 + kt * 2 + c32) * 64 + l2] = o;
  }
}

// ---------------------------------------------------------------------------
// Causal flash attention v4: barrier-free, LDS-free. 1 wave = 16 q-rows.
// K and Vt pre-packed in MFMA fragment order -> every fragment load is one
// coalesced global_load_dwordx4 (16B/lane), L1/L2-served (KV slice per
// (b,h) = 512KB packed, L2-resident).
// Grid 4096 x 64thr; id = qw*32 + bh so id%8 = bh%8 -> same-bh blocks land
// on one XCD under round-robin dispatch (L2 locality heuristic, speed-only).
// Heavy q-tiles first: qt = 31 - (qw>>2). 16 waves/CU (launch_bounds(64,4)).
// ---------------------------------------------------------------------------
__global__ __launch_bounds__(64, 4) void attn_mfma4(
    const u16* __restrict__ Qb,
    const uint4* __restrict__ PK,
    const uint4* __restrict__ PVp,
    u16* __restrict__ Y) {
  const int id = blockIdx.x;           // 0..4095
  const int bh = id & 31;
  const int qw = id >> 5;              // 0..127
  const int qt = 31 - (qw >> 2);       // heavy tiles dispatched first
  const int wq = qw & 3;               // 16-row group within 64-row tile
  const int b = bh >> 4, h = bh & 15;
  const int l = threadIdx.x;           // 0..63
  const int lo = l & 15, hi = l >> 4;
  const int hi4 = hi * 4;
  const int rloc = wq * 16 + lo;       // q-row within the 64-row tile

  // ---- Q B-fragments (row-major gather, once)
  FragU qf[2];
  {
    const char* qc = (const char*)(Qb +
        ((size_t)(b * NL + qt * 64 + rloc)) * ND + h * 64);
    uint2 a0 = *(const uint2*)(qc + hi * 8);
    uint2 b0 = *(const uint2*)(qc + hi * 8 + 32);
    uint2 a1 = *(const uint2*)(qc + hi * 8 + 64);
    uint2 b1 = *(const uint2*)(qc + hi * 8 + 96);
    qf[0].u[0] = a0.x; qf[0].u[1] = a0.y; qf[0].u[2] = b0.x; qf[0].u[3] = b0.y;
    qf[1].u[0] = a1.x; qf[1].u[1] = a1.y; qf[1].u[2] = b1.x; qf[1].u[3] = b1.y;
  }

  // fragment bases (lane folded in; chunk strides are multiples of 64 uint4)
  // K chunk: ((b*128 + kt*4 + kg)*32 + 2h + c32)*64 + l
  const uint4* kfb = PK + (((size_t)b * 128) * 32 + 2 * h) * 64 + l;
  // V chunk: ((bh*4 + et)*64 + kt*2 + c32)*64 + l
  const uint4* vfb = PVp + ((size_t)bh * 4 * 64) * 64 + l;

  float m_run = -1e30f, l_run = 0.f;
  f32x4 y[4];
#pragma unroll
  for (int et = 0; et < 4; ++et) y[et] = (f32x4){0.f, 0.f, 0.f, 0.f};

  for (int kt = 0; kt <= qt; ++kt) {
    // ---- K fragments (8 coalesced dwordx4)
    FragU kf[8];
#pragma unroll
    for (int kg = 0; kg < 4; ++kg)
#pragma unroll
      for (int c32 = 0; c32 < 2; ++c32)
        *(uint4*)kf[kg * 2 + c32].u =
            kfb[((size_t)(kt * 4 + kg) * 32 + c32) * 64];

    // ---- S^T = K * Q^T : s[kg][reg] = S[row=rloc][key = kg*16+hi4+reg]
    f32x4 s[4];
    __builtin_amdgcn_s_setprio(1);
#pragma unroll
    for (int kg = 0; kg < 4; ++kg) {
      s[kg] = (f32x4){0.f, 0.f, 0.f, 0.f};
      s[kg] = __builtin_amdgcn_mfma_f32_16x16x32_bf16(kf[kg * 2 + 0].v, qf[0].v,
                                                      s[kg], 0, 0, 0);
      s[kg] = __builtin_amdgcn_mfma_f32_16x16x32_bf16(kf[kg * 2 + 1].v, qf[1].v,
                                                      s[kg], 0, 0, 0);
    }
    __builtin_amdgcn_s_setprio(0);

    // ---- V fragments issued now; latency hides under softmax
    FragU vf[8];
#pragma unroll
    for (int et = 0; et < 4; ++et)
#pragma unroll
      for (int c32 = 0; c32 < 2; ++c32)
        *(uint4*)vf[et * 2 + c32].u =
            vfb[(size_t)(et * 64 + kt * 2 + c32) * 64];

    // ---- causal mask (diagonal tile only)
    if (kt == qt) {
#pragma unroll
      for (int kg = 0; kg < 4; ++kg)
#pragma unroll
        for (int reg = 0; reg < 4; ++reg)
          if (kg * 16 + hi4 + reg > rloc) s[kg][reg] = -1e30f;
    }

    // ---- online softmax (base 2), defer-max
    float mt = s[0][0];
#pragma unroll
    for (int kg = 0; kg < 4; ++kg)
#pragma unroll
      for (int reg = 0; reg < 4; ++reg) mt = fmaxf(mt, s[kg][reg]);
    mt = fmaxf(mt, __shfl_xor(mt, 16));
    mt = fmaxf(mt, __shfl_xor(mt, 32));
    if (__any(mt > m_run + 8.f)) {       // wave-uniform branch
      const float mnew = fmaxf(m_run, mt);
      const float corr = exp2f(m_run - mnew);
      m_run = mnew;
      l_run *= corr;
      const float c0 = __shfl(corr, hi4 + 0);
      const float c1 = __shfl(corr, hi4 + 1);
      const float c2 = __shfl(corr, hi4 + 2);
      const float c3 = __shfl(corr, hi4 + 3);
#pragma unroll
      for (int et = 0; et < 4; ++et) {
        y[et][0] *= c0; y[et][1] *= c1; y[et][2] *= c2; y[et][3] *= c3;
      }
    }
    float ps = 0.f;
#pragma unroll
    for (int kg = 0; kg < 4; ++kg)
#pragma unroll
      for (int reg = 0; reg < 4; ++reg) {
        float e = exp2f(s[kg][reg] - m_run);
        s[kg][reg] = e;
        ps += e;
      }
    ps += __shfl_xor(ps, 16);
    ps += __shfl_xor(ps, 32);
    l_run += ps;

    // ---- P A-fragments via casts (v_cvt_pk_bf16_f32)
    FragU pa0, pa1;
#pragma unroll
    for (int kg = 0; kg < 2; ++kg)
#pragma unroll
      for (int reg = 0; reg < 4; ++reg) {
        pa0.v[kg * 4 + reg] = (__bf16)s[kg][reg];
        pa1.v[kg * 4 + reg] = (__bf16)s[kg + 2][reg];
      }

    // ---- PV
    __builtin_amdgcn_s_setprio(1);
#pragma unroll
    for (int et = 0; et < 4; ++et) {
      y[et] = __builtin_amdgcn_mfma_f32_16x16x32_bf16(pa0.v, vf[et * 2 + 0].v,
                                                      y[et], 0, 0, 0);
      y[et] = __builtin_amdgcn_mfma_f32_16x16x32_bf16(pa1.v, vf[et * 2 + 1].v,
                                                      y[et], 0, 0, 0);
    }
    __builtin_amdgcn_s_setprio(0);
  }

  // ---- epilogue: normalize and store (rows hi4+reg, col et*16+lo)
  const float li0 = 1.f / __shfl(l_run, hi4 + 0);
  const float li1 = 1.f / __shfl(l_run, hi4 + 1);
  const float li2 = 1.f / __shfl(l_run, hi4 + 2);
  const float li3 = 1.f / __shfl(l_run, hi4 + 3);
  __bf16* Yb16 = (__bf16*)Y;
  const size_t ybase = (size_t)(b * NL + qt * 64 + wq * 16) * ND + h * 64;
#pragma unroll
  for (int et = 0; et < 4; ++et) {
    Yb16[ybase + (size_t)(hi4 + 0) * ND + et * 16 + lo] = (__bf16)(y[et][0] * li0);
    Yb16[ybase + (size_t)(hi4 + 1) * ND + et * 16 + lo] = (__bf16)(y[et][1] * li1);
    Yb16[ybase + (size_t)(hi4 + 2) * ND + et * 16 + lo] = (__bf16)(y[et][2] * li2);
    Yb16[ybase + (size_t)(hi4 + 3) * ND + et * 16 + lo] = (__bf16)(y[et][3] * li3);
  }
}

// ---------------------------------------------------------------------------
extern "C" void kernel_launch(void* const* d_in, const int* in_sizes, int n_in,
                              void* d_out, int out_size, void* d_ws,
                              size_t ws_size, hipStream_t stream) {
  const float* x  = (const float*)d_in[0];
  const float* Wq = (const float*)d_in[1];
  const float* Wk = (const float*)d_in[2];
  const float* Wv = (const float*)d_in[3];
  const float* Wo = (const float*)d_in[4];
  float* out = (float*)d_out;

  // workspace layout (46.25 MB), 8MB regions with liveness-based reuse:
  //   R0 [0,8)   Qb  (gemm->attn)        -> PWo (after attn)
  //   R1 [8,16)  Kb  (gemm->pack_k)      -> Yb  (attn output)
  //   R2 [16,24) Vb  (gemm->pack_vt)     -> PK  (pack_k->attn)
  //   R3 [24,32) PVp (pack_vt->attn)
  //   R4 [32,40) PA  (pack_a->gemm_qkv)  -> PY  (pack_a(Yb)->gemm_out)
  //   R5 [40,46) PWq|PWk|PWv (2MB each, dead after gemm_qkv)
  //   [46,46.25) rope tab
  char* ws = (char*)d_ws;
  u16*   Qb  = (u16*)(ws);
  u16*   Kb  = (u16*)(ws + ((size_t)8 << 20));
  u16*   Yb  = Kb;
  u16*   Vb  = (u16*)(ws + ((size_t)16 << 20));
  uint4* PK  = (uint4*)Vb;
  uint4* PVp = (uint4*)(ws + ((size_t)24 << 20));
  uint4* PA  = (uint4*)(ws + ((size_t)32 << 20));
  uint4* PY  = PA;
  uint4* PWq = (uint4*)(ws + ((size_t)40 << 20));
  uint4* PWk = (uint4*)(ws + ((size_t)42 << 20));
  uint4* PWv = (uint4*)(ws + ((size_t)44 << 20));
  uint4* PWo = (uint4*)Qb;
  u32*   tab = (u32*)(ws + ((size_t)46 << 20));

  dim3 blk(256);

  pack_w<<<dim3(64, 3), blk, 0, stream>>>(Wq, Wk, Wv, PWq, PWk, PWv);
  pack_a<true><<<dim3(NM / 16), blk, 0, stream>>>(x, PA);
  gemm_qkv<<<dim3(8, 32, 3), blk, 0, stream>>>(PA, PWq, PWk, PWv, Qb, Kb, Vb);
  rope_tab<<<dim3(NL * 32 / 256), blk, 0, stream>>>(tab);
  rope_apply<<<dim3(2 * NM * (ND / 8) / 256), blk, 0, stream>>>(
      (u32*)Qb, (u32*)Kb, tab);
  pack_vt<<<dim3(NL / 64, NB * NH), blk, 0, stream>>>(Vb, PVp);     // Vb -> PVp
  pack_a<false><<<dim3(NM / 16), blk, 0, stream>>>(Kb, PK);         // Kb -> PK
  attn_mfma4<<<dim3(128 * 32), dim3(64), 0, stream>>>(Qb, PK, PVp, Yb);
  pack_a<false><<<dim3(NM / 16), blk, 0, stream>>>(Yb, PY);
  pack_w<<<dim3(64, 1), blk, 0, stream>>>(Wo, Wo, Wo, PWo, PWo, PWo);
  gemm_out<<<dim3(8, 32), blk, 0, stream>>>(PY, PWo, out);
}